// Round 10
// baseline (461.438 us; speedup 1.0000x reference)
//
#include <hip/hip_runtime.h>
#include <math.h>

#define N_TOT 32768
#define NNBR 15
#define APW 8
#define ELPH 40
#define ETP 20
#define PLP 20

// k_pre block ranges
#define KNB 4096
#define FRB 128
#define PRB 3392

// k_eq block ranges
#define EB 1920

typedef __attribute__((ext_vector_type(8))) _Float16 f16x8;
typedef __attribute__((ext_vector_type(2))) _Float16 f16x2;
typedef __attribute__((ext_vector_type(4))) float f32x4;

#define CBAR() __asm__ volatile("" ::: "memory")
#define PAIR(v, c) __builtin_shufflevector(v, v, 2 * (c), 2 * (c) + 1)

__device__ __forceinline__ _Float16 f2h(float x) { return (_Float16)x; }

__device__ __forceinline__ float fdot2(f16x2 a, f16x2 b, float c) {
  float d;
  asm("v_dot2_f32_f16 %0, %1, %2, %3" : "=v"(d) : "v"(a), "v"(b), "v"(c));
  return d;
}

template <int CTRL>
__device__ __forceinline__ float dpp_mov_f32(float x) {
  return __int_as_float(
      __builtin_amdgcn_update_dpp(0, __float_as_int(x), CTRL, 0xf, 0xf, true));
}

template <int CTRL>
__device__ __forceinline__ unsigned dpp_max_u32(unsigned x) {
  unsigned y = (unsigned)__builtin_amdgcn_update_dpp(0, (int)x, CTRL, 0xf, 0xf, true);
  return y > x ? y : x;
}

template <int CTRL>
__device__ __forceinline__ unsigned long long dpp_max_u64(unsigned long long x) {
  unsigned lo = (unsigned)__builtin_amdgcn_update_dpp(
      0, (int)(unsigned)x, CTRL, 0xf, 0xf, true);
  unsigned hi = (unsigned)__builtin_amdgcn_update_dpp(
      0, (int)(unsigned)(x >> 32), CTRL, 0xf, 0xf, true);
  unsigned long long y = ((unsigned long long)hi << 32) | lo;
  return y > x ? y : x;
}

// top-3 insert, value-only strict compare; preserves j-ascending order on ties
__device__ __forceinline__ void ins3v(unsigned s, int j,
                                      unsigned& m1v, int& i1,
                                      unsigned& m2v, int& i2,
                                      unsigned& m3v, int& i3) {
  bool g1 = s > m1v;
  unsigned t = g1 ? m1v : s;  int it = g1 ? i1 : j;
  m1v = g1 ? s : m1v;         i1  = g1 ? j  : i1;
  bool g2 = t > m2v;
  unsigned u = g2 ? m2v : t;  int iu = g2 ? i2 : it;
  m2v = g2 ? t : m2v;         i2  = g2 ? it : i2;
  bool g3 = u > m3v;
  m3v = g3 ? u : m3v;         i3  = g3 ? iu : i3;
}

// ---------------------------------------------------------------- fused pre: kNN + frames + weight prep + hinit
__global__ __launch_bounds__(256) void k_pre(
    const float* __restrict__ tert, const float* __restrict__ noise,
    int* __restrict__ nbr, float* __restrict__ pos, float* __restrict__ R,
    const float* __restrict__ wq, const float* __restrict__ wk,
    const float* __restrict__ wv, const float* __restrict__ wo,
    const float* __restrict__ w1, const float* __restrict__ w2,
    const float* __restrict__ w3, _Float16* __restrict__ wbt,
    _Float16* __restrict__ wqk, _Float16* __restrict__ wpe,
    const float* __restrict__ pw, _Float16* __restrict__ wct,
    const float* __restrict__ ew, const float* __restrict__ ebias,
    _Float16* __restrict__ h) {
  __shared__ float posL[512 * 3];
  __shared__ float hvS[128];
  int bb = blockIdx.x, tid = threadIdx.x;
  if (bb < KNB) {
    // ---- kNN: 8 rows per block (2 per wave), 32-bit DPP select
    int b = bb >> 6;
    int n0 = b << 9;
    for (int i = tid; i < 1536; i += 256) {
      int r = i / 3, c = i - r * 3;
      posL[i] = tert[(size_t)(n0 + r) * 9 + 3 + c];
    }
    __syncthreads();
    int wave = tid >> 6, lane = tid & 63;
    int l = lane & 31;
    int rloc = (bb & 63) * 8 + wave * 2 + (lane >> 5);
    int row = n0 + rloc;
    const float* nrow = noise + (size_t)row * 512;
    float pix = posL[rloc * 3 + 0];
    float piy = posL[rloc * 3 + 1];
    float piz = posL[rloc * 3 + 2];
    unsigned m1v = 0u, m2v = 0u, m3v = 0u;
    int i1 = 0, i2 = 0, i3 = 0;
#pragma unroll
    for (int jj = 0; jj < 16; jj++) {
      int j = l + jj * 32;
      float dx = posL[j * 3 + 0] - pix;
      float dy = posL[j * 3 + 1] - piy;
      float dz = posL[j * 3 + 2] - piz;
      float c = -sqrtf(dx * dx + dy * dy + dz * dz) + 3.f * nrow[j];
      unsigned u = __float_as_uint(c);
      unsigned s = u ^ (unsigned)(((int)u >> 31) | (int)0x80000000);
      ins3v(s, j, m1v, i1, m2v, i2, m3v, i3);
    }
    int jmine = 0;
#pragma unroll 1
    for (int it = 0; it < NNBR; it++) {
      unsigned r = m1v;
      r = dpp_max_u32<0x111>(r);  // row_shr:1
      r = dpp_max_u32<0x112>(r);  // row_shr:2
      r = dpp_max_u32<0x114>(r);  // row_shr:4
      r = dpp_max_u32<0x118>(r);  // row_shr:8
      r = dpp_max_u32<0x142>(r);  // row_bcast:15 -> lanes 31/63 hold half-maxes
      unsigned gA = (unsigned)__builtin_amdgcn_readlane((int)r, 31);
      unsigned gB = (unsigned)__builtin_amdgcn_readlane((int)r, 63);
      unsigned gsel = (lane & 32) ? gB : gA;
      bool match = (m1v == gsel);
      unsigned long long mk = __ballot((int)match);
      unsigned mA = (unsigned)mk, mB = (unsigned)(mk >> 32);
      int jA = __builtin_amdgcn_readlane(i1, __ffs(mA) - 1);
      int jB = __builtin_amdgcn_readlane(i1, 31 + __ffs(mB));
      if (__popc(mA) > 1 || __popc(mB) > 1) {
        // rare exact tie-break: packed u64 reduce (value, 511-j)
        unsigned long long pk = ((unsigned long long)m1v << 9) | (unsigned)(511 - i1);
        pk = dpp_max_u64<0x111>(pk);
        pk = dpp_max_u64<0x112>(pk);
        pk = dpp_max_u64<0x114>(pk);
        pk = dpp_max_u64<0x118>(pk);
        pk = dpp_max_u64<0x142>(pk);
        unsigned pA = (unsigned)__builtin_amdgcn_readlane((int)(unsigned)pk, 31);
        unsigned pB = (unsigned)__builtin_amdgcn_readlane((int)(unsigned)pk, 63);
        if (__popc(mA) > 1) jA = 511 - (int)(pA & 511u);
        if (__popc(mB) > 1) jB = 511 - (int)(pB & 511u);
      }
      int j = (lane & 32) ? jB : jA;
      if (l == it) jmine = j;
      bool win = match && (i1 == j);
      if (win) { m1v = m2v; i1 = i2; m2v = m3v; i2 = i3; m3v = 0u; }
      // rare: winner exhausted its cached top-3 -> exact rescan below (value, index) threshold
      if (__any((int)(win && m1v == 0u))) {
        if (win && m1v == 0u) {
          unsigned gv = gsel; int gj = j;
          unsigned a1 = 0u, a2 = 0u, a3 = 0u;
          int b1i = 0, b2i = 0, b3i = 0;
#pragma unroll 1
          for (int jj = 0; jj < 16; jj++) {
            int j2 = l + jj * 32;
            float dx = posL[j2 * 3 + 0] - pix;
            float dy = posL[j2 * 3 + 1] - piy;
            float dz = posL[j2 * 3 + 2] - piz;
            float c = -sqrtf(dx * dx + dy * dy + dz * dz) + 3.f * nrow[j2];
            unsigned u = __float_as_uint(c);
            unsigned s = u ^ (unsigned)(((int)u >> 31) | (int)0x80000000);
            bool keep = (s < gv) || (s == gv && j2 > gj);
            ins3v(keep ? s : 0u, j2, a1, b1i, a2, b2i, a3, b3i);
          }
          m1v = a1; i1 = b1i; m2v = a2; i2 = b2i; m3v = a3; i3 = b3i;
        }
      }
    }
    if (l < NNBR) nbr[(size_t)row * NNBR + l] = n0 + jmine;
  } else if (bb < KNB + FRB) {
    // ---- frames
    int n = (bb - KNB) * 256 + tid;
    if (n >= N_TOT) return;
    float px = tert[n * 9 + 3], py = tert[n * 9 + 4], pz = tert[n * 9 + 5];
    pos[n * 3 + 0] = px; pos[n * 3 + 1] = py; pos[n * 3 + 2] = pz;
    int i0 = (n > 0) ? (n - 1) : 0;
    int i1 = (n < N_TOT - 1) ? n : (N_TOT - 2);
    float ax = tert[(i0 + 1) * 9 + 3] - tert[i0 * 9 + 3];
    float ay = tert[(i0 + 1) * 9 + 4] - tert[i0 * 9 + 4];
    float az = tert[(i0 + 1) * 9 + 5] - tert[i0 * 9 + 5];
    float il = 1.f / (sqrtf(ax * ax + ay * ay + az * az) + 1e-8f);
    float ux = ax * il, uy = ay * il, uz = az * il;
    float cx = tert[(i1 + 1) * 9 + 3] - tert[i1 * 9 + 3];
    float cy = tert[(i1 + 1) * 9 + 4] - tert[i1 * 9 + 4];
    float cz = tert[(i1 + 1) * 9 + 5] - tert[i1 * 9 + 5];
    il = 1.f / (sqrtf(cx * cx + cy * cy + cz * cz) + 1e-8f);
    float vx = cx * il, vy = cy * il, vz = cz * il;
    float bx = ux - vx, by = uy - vy, bz = uz - vz;
    il = 1.f / (sqrtf(bx * bx + by * by + bz * bz) + 1e-8f);
    bx *= il; by *= il; bz *= il;
    float nx = uy * vz - uz * vy;
    float ny = uz * vx - ux * vz;
    float nz = ux * vy - uy * vx;
    il = 1.f / (sqrtf(nx * nx + ny * ny + nz * nz) + 1e-8f);
    nx *= il; ny *= il; nz *= il;
    float ex = by * nz - bz * ny;
    float ey = bz * nx - bx * nz;
    float ez = bx * ny - by * nx;
    float* Rn = R + (size_t)n * 9;
    Rn[0] = bx; Rn[1] = nx; Rn[2] = ex;
    Rn[3] = by; Rn[4] = ny; Rn[5] = ey;
    Rn[6] = bz; Rn[7] = nz; Rn[8] = ez;
  } else {
    int pb2 = bb - (KNB + FRB);
    if (pb2 < 1344) {
      // ---- dense weight prep: fp32 [k][n] -> fp16 [n][k]
      int idx = pb2 * 256 + tid;
      int lL = idx / (7 * 16384);
      int r = idx % (7 * 16384);
      int w = r / 16384;
      int e = r % 16384;
      int k = e >> 7, n = e & 127;
      float val;
      switch (w) {
        case 0: val = wq[(size_t)lL * 16384 + e]; break;
        case 1: val = wk[(size_t)lL * 157 * 128 + e]; break;
        case 2: val = wv[(size_t)lL * 157 * 128 + e]; break;
        case 3: val = wo[(size_t)lL * 16384 + e]; break;
        case 4: val = w1[(size_t)lL * 16384 + e]; break;
        case 5: val = w2[(size_t)lL * 16384 + e]; break;
        default: val = w3[(size_t)lL * 16384 + e]; break;
      }
      wbt[(size_t)(lL * 7 + w) * 16384 + n * 128 + k] = f2h(val);
    } else if (pb2 < 1728) {
      // ---- Wqk composite (j = h*32+e layout)
      int idx = (pb2 - 1344) * 256 + tid;
      int lL = idx / 32768;
      int r = idx % 32768;
      int blk = r >> 14;
      int jp = (r >> 7) & 127;
      int c = r & 127;
      int j = blk * 128 + jp;
      int hh = j >> 5, e = j & 31;
      float val = 0.f;
      if (e < 29) {
        const float* wqp = wq + (size_t)lL * 16384 + (size_t)c * 128 + hh * 16;
        const float* wkp = wk + (size_t)lL * 157 * 128 + (size_t)(128 + e) * 128 + hh * 16;
        float s = 0.f;
#pragma unroll
        for (int d = 0; d < 16; d++) s = fmaf(wqp[d], wkp[d], s);
        val = 0.25f * s;
      }
      wqk[(size_t)idx] = f2h(val);
    } else if (pb2 < 2112) {
      // ---- wpe = Wv_e'' @ Wo (j = e*8+h layout)
      int idx = (pb2 - 1728) * 256 + tid;
      int lL = idx / 32768;
      int r = idx % 32768;
      int blk = r >> 14;
      int cout = (r >> 7) & 127;
      int jp = r & 127;
      int j = blk * 128 + jp;
      float val = 0.f;
      if (j < 232) {
        int e = j >> 3, hh = j & 7;
        const float* wvp = wv + (size_t)lL * 157 * 128 + (size_t)(128 + e) * 128 + hh * 16;
        const float* wop = wo + (size_t)lL * 16384 + (size_t)(hh * 16) * 128 + cout;
#pragma unroll
        for (int d = 0; d < 16; d++) val = fmaf(wvp[d], wop[d * 128], val);
      }
      wpe[(size_t)idx] = f2h(val);
    } else if (pb2 < 2880) {
      // ---- conv weight prep
      int idx = (pb2 - 2112) * 256 + tid;
      int kt = idx % 3;
      int rest = idx / 3;
      int i = rest % 128; rest /= 128;
      int oo = rest % 128;
      int s = rest / 128;
      wct[(((size_t)s * 3 + kt) * 128 + oo) * 128 + i] = f2h(pw[idx]);
    } else {
      // ---- h init (virtual grid of 512 blocks)
      int vb = pb2 - 2880;
      if (tid < 128) {
        float s = ebias[tid];
#pragma unroll
        for (int i = 0; i < 27; i++) s += ew[i * 128 + tid];
        hvS[tid] = s;
      }
      __syncthreads();
      size_t total = (size_t)N_TOT * 128;
      for (size_t j = (size_t)vb * 256 + tid; j < total; j += (size_t)512 * 256)
        h[j] = f2h(hvS[j & 127]);
    }
  }
}

// ---------------------------------------------------------------- GEMM helpers (round-4 geometry)
template <int NTHR>
__device__ __forceinline__ void stage_w_async(const _Float16* __restrict__ W,
                                              _Float16* Ws, int tid) {
  int wv = tid >> 6, lane = tid & 63;
  constexpr int ITERS = 16384 / (NTHR * 8);
#pragma unroll
  for (int it = 0; it < ITERS; it++) {
    int base = it * (NTHR * 8) + wv * 512;    // f16 units, wave-uniform
    int off = base + lane * 8;                // this lane's linear dest
    int row = off >> 7;
    int cL = (off >> 3) & 15;
    int cS = cL ^ (row & 7);
    const _Float16* src = W + ((size_t)row << 7) + (cS << 3);
    __builtin_amdgcn_global_load_lds(
        (const __attribute__((address_space(1))) void*)src,
        (__attribute__((address_space(3))) void*)(Ws + base), 16, 0, 0);
  }
}
template <int NTHR, int ROWS>
__device__ __forceinline__ void stage_x(const _Float16* __restrict__ src, _Float16* X,
                                        int tid, int rowstride) {
  for (int j = tid; j < ROWS * 16; j += NTHR) {
    int row = j >> 4, seg = (j & 15) * 8;
    *(uint4*)&X[row * 136 + seg] = *(const uint4*)(src + (size_t)row * rowstride + seg);
  }
}
template <bool RESET>
__device__ __forceinline__ void gemm_tile_t(const _Float16* X, const _Float16* Ws,
                                            int wrow, int l16, int quad, f32x4 acc[8]) {
  if (RESET) {
#pragma unroll
    for (int t = 0; t < 8; t++) acc[t] = (f32x4){0.f, 0.f, 0.f, 0.f};
  }
#pragma unroll
  for (int kk = 0; kk < 4; kk++) {
    f16x8 a = *(const f16x8*)&X[(wrow + l16) * 136 + kk * 32 + quad * 8];
#pragma unroll
    for (int t = 0; t < 8; t++) {
      int rw = t * 16 + l16;
      f16x8 b = *(const f16x8*)&Ws[(rw << 7) + ((((kk << 2) + quad) ^ (rw & 7)) << 3)];
      acc[t] = __builtin_amdgcn_mfma_f32_16x16x32_f16(a, b, acc[t], 0, 0, 0);
    }
  }
}

// ---------------------------------------------------------------- attn row body (shared by k_attn / k_ap)
__device__ __forceinline__ void attn_row(int n, int lane,
                                         const _Float16* __restrict__ q,
                                         const _Float16* __restrict__ hk,
                                         const _Float16* __restrict__ hv,
                                         const int* __restrict__ nbr,
                                         const _Float16* __restrict__ edge,
                                         const _Float16* __restrict__ qkw,
                                         _Float16* __restrict__ pe_g,
                                         _Float16* el, float* et, float* pl, int* nbl,
                                         float& ox, float& oy) {
  int h8 = lane & 7, k2 = lane >> 3, c2 = lane * 2, h5 = lane >> 3;
  int kst = lane >> 2, gst = lane & 3;
  if (lane < 60) {
    f16x8 ev = *(const f16x8*)(edge + ((size_t)n * 15 + kst) * 32 + gst * 8);
    *(f16x8*)&el[kst * ELPH + gst * 8] = ev;
    int ebs = gst * 8;
    et[(ebs + 0) * ETP + kst] = (float)ev[0];
    et[(ebs + 1) * ETP + kst] = (float)ev[1];
    et[(ebs + 2) * ETP + kst] = (float)ev[2];
    et[(ebs + 3) * ETP + kst] = (float)ev[3];
    et[(ebs + 4) * ETP + kst] = (float)ev[4];
    et[(ebs + 5) * ETP + kst] = (float)ev[5];
    et[(ebs + 6) * ETP + kst] = (float)ev[6];
    et[(ebs + 7) * ETP + kst] = (float)ev[7];
  }
  if (lane < 15) nbl[lane] = nbr[(size_t)n * NNBR + lane];
  const _Float16* qs = qkw + (size_t)n * 256 + h8 * 32;
  f16x8 w0 = *(const f16x8*)qs, w1 = *(const f16x8*)(qs + 8);
  f16x8 w2 = *(const f16x8*)(qs + 16), w3 = *(const f16x8*)(qs + 24);
  const _Float16* qp = q + (size_t)n * 128 + h8 * 16;
  f16x8 qa = *(const f16x8*)qp, qb = *(const f16x8*)(qp + 8);
  CBAR();
#pragma unroll
  for (int p = 0; p < 2; p++) {
    int k = k2 + p * 8;
    if (k < 15) {
      int m = nbl[k];
      const _Float16* hkp = hk + (size_t)m * 128 + h8 * 16;
      f16x8 ha = *(const f16x8*)hkp, hb = *(const f16x8*)(hkp + 8);
      float d0 = 0.f, d1 = 0.f;
      d0 = fdot2(PAIR(qa, 0), PAIR(ha, 0), d0);
      d1 = fdot2(PAIR(qa, 1), PAIR(ha, 1), d1);
      d0 = fdot2(PAIR(qa, 2), PAIR(ha, 2), d0);
      d1 = fdot2(PAIR(qa, 3), PAIR(ha, 3), d1);
      d0 = fdot2(PAIR(qb, 0), PAIR(hb, 0), d0);
      d1 = fdot2(PAIR(qb, 1), PAIR(hb, 1), d1);
      d0 = fdot2(PAIR(qb, 2), PAIR(hb, 2), d0);
      d1 = fdot2(PAIR(qb, 3), PAIR(hb, 3), d1);
      f16x8 l0 = *(const f16x8*)&el[k * ELPH + 0];
      f16x8 l1 = *(const f16x8*)&el[k * ELPH + 8];
      f16x8 l2 = *(const f16x8*)&el[k * ELPH + 16];
      f16x8 l3 = *(const f16x8*)&el[k * ELPH + 24];
      float e0 = 0.f, e1 = 0.f;
      e0 = fdot2(PAIR(l0, 0), PAIR(w0, 0), e0);
      e1 = fdot2(PAIR(l0, 1), PAIR(w0, 1), e1);
      e0 = fdot2(PAIR(l0, 2), PAIR(w0, 2), e0);
      e1 = fdot2(PAIR(l0, 3), PAIR(w0, 3), e1);
      e0 = fdot2(PAIR(l1, 0), PAIR(w1, 0), e0);
      e1 = fdot2(PAIR(l1, 1), PAIR(w1, 1), e1);
      e0 = fdot2(PAIR(l1, 2), PAIR(w1, 2), e0);
      e1 = fdot2(PAIR(l1, 3), PAIR(w1, 3), e1);
      e0 = fdot2(PAIR(l2, 0), PAIR(w2, 0), e0);
      e1 = fdot2(PAIR(l2, 1), PAIR(w2, 1), e1);
      e0 = fdot2(PAIR(l2, 2), PAIR(w2, 2), e0);
      e1 = fdot2(PAIR(l2, 3), PAIR(w2, 3), e1);
      e0 = fdot2(PAIR(l3, 0), PAIR(w3, 0), e0);
      e1 = fdot2(PAIR(l3, 1), PAIR(w3, 1), e1);
      e0 = fdot2(PAIR(l3, 2), PAIR(w3, 2), e0);
      e1 = fdot2(PAIR(l3, 3), PAIR(w3, 3), e1);
      pl[h8 * PLP + k] = fmaf(0.25f, d0 + d1, e0 + e1);
    } else {
      pl[h8 * PLP + 15] = -1e30f;
    }
  }
  CBAR();
  {
    int hh = lane >> 3, g = lane & 7;
    float va = pl[hh * PLP + g];
    float vb = pl[hh * PLP + 8 + g];
    float mx = fmaxf(va, vb);
    mx = fmaxf(mx, dpp_mov_f32<0xB1>(mx));
    mx = fmaxf(mx, dpp_mov_f32<0x4E>(mx));
    mx = fmaxf(mx, dpp_mov_f32<0x141>(mx));
    float ea = __expf(va - mx), eb = __expf(vb - mx);
    float s = ea + eb;
    s += dpp_mov_f32<0xB1>(s);
    s += dpp_mov_f32<0x4E>(s);
    s += dpp_mov_f32<0x141>(s);
    float inv = 1.f / s;
    pl[hh * PLP + g] = ea * inv;
    pl[hh * PLP + 8 + g] = eb * inv;
  }
  CBAR();
  _Float16* peo = pe_g + (size_t)n * 256;
#pragma unroll
  for (int p = 0; p < 4; p++) {
    int j = p * 64 + lane;
    float s = 0.f;
    if (j < 232) {
      int e = j >> 3, hh = j & 7;
      f32x4 p0 = *(const f32x4*)&pl[hh * PLP + 0];
      f32x4 p1 = *(const f32x4*)&pl[hh * PLP + 4];
      f32x4 p2 = *(const f32x4*)&pl[hh * PLP + 8];
      f32x4 p3 = *(const f32x4*)&pl[hh * PLP + 12];
      f32x4 t0 = *(const f32x4*)&et[e * ETP + 0];
      f32x4 t1 = *(const f32x4*)&et[e * ETP + 4];
      f32x4 t2 = *(const f32x4*)&et[e * ETP + 8];
      f32x4 t3 = *(const f32x4*)&et[e * ETP + 12];
      s = p0[0]*t0[0] + p0[1]*t0[1] + p0[2]*t0[2] + p0[3]*t0[3]
        + p1[0]*t1[0] + p1[1]*t1[1] + p1[2]*t1[2] + p1[3]*t1[3]
        + p2[0]*t2[0] + p2[1]*t2[1] + p2[2]*t2[2] + p2[3]*t2[3]
        + p3[0]*t3[0] + p3[1]*t3[1] + p3[2]*t3[2] + p3[3]*t3[3];
    }
    peo[j] = f2h(s);
  }
  float pk[16];
  *(f32x4*)&pk[0]  = *(const f32x4*)&pl[h5 * PLP + 0];
  *(f32x4*)&pk[4]  = *(const f32x4*)&pl[h5 * PLP + 4];
  *(f32x4*)&pk[8]  = *(const f32x4*)&pl[h5 * PLP + 8];
  *(f32x4*)&pk[12] = *(const f32x4*)&pl[h5 * PLP + 12];
  ox = 0.f; oy = 0.f;
#pragma unroll
  for (int k = 0; k < 15; k++) {
    int m = nbl[k];
    f16x2 hh2 = *(const f16x2*)(hv + (size_t)m * 128 + c2);
    ox = fmaf(pk[k], (float)hh2[0], ox);
    oy = fmaf(pk[k], (float)hh2[1], oy);
  }
  CBAR();
}

// ---------------------------------------------------------------- post GEMM-chain body (shared by k_post / k_ap); X preloaded with o
__device__ __forceinline__ void post_body(
    const _Float16* __restrict__ pe_g, _Float16* __restrict__ h,
    const _Float16* __restrict__ Wot, const _Float16* __restrict__ Wpe0,
    const _Float16* __restrict__ Wpe1,
    const _Float16* __restrict__ W1t, const float* __restrict__ B1,
    const _Float16* __restrict__ W2t, const float* __restrict__ B2,
    const _Float16* __restrict__ W3t, const float* __restrict__ B3,
    const _Float16* __restrict__ Wqt, const _Float16* __restrict__ Wkt,
    const _Float16* __restrict__ Wvt, const _Float16* __restrict__ Wqk0,
    const _Float16* __restrict__ Wqk1,
    _Float16* __restrict__ qo, _Float16* __restrict__ hko,
    _Float16* __restrict__ hvo, _Float16* __restrict__ qkwo, int do_qkv,
    _Float16* X, _Float16* Ws, int tid, int r0) {
  int lane = tid & 63, quad = lane >> 4, l16 = lane & 15, wrow = (tid >> 6) * 16;
  f32x4 acc[8], hres[8];
  stage_w_async<256>(Wot, Ws, tid);
  __syncthreads();
  gemm_tile_t<true>(X, Ws, wrow, l16, quad, acc);
  const _Float16* wpes[2] = {Wpe0, Wpe1};
#pragma unroll 1
  for (int blk = 0; blk < 2; blk++) {
    __syncthreads();
    stage_x<256, 64>(pe_g + (size_t)r0 * 256 + blk * 128, X, tid, 256);
    stage_w_async<256>(wpes[blk], Ws, tid);
    __syncthreads();
    gemm_tile_t<false>(X, Ws, wrow, l16, quad, acc);
  }
#pragma unroll
  for (int t = 0; t < 8; t++) {
    int col = t * 16 + l16;
#pragma unroll
    for (int r = 0; r < 4; r++)
      hres[t][r] = acc[t][r] + (float)h[(size_t)(r0 + wrow + quad * 4 + r) * 128 + col];
  }
  __syncthreads();
#pragma unroll
  for (int t = 0; t < 8; t++) {
    int col = t * 16 + l16;
#pragma unroll
    for (int r = 0; r < 4; r++)
      X[(wrow + quad * 4 + r) * 136 + col] = f2h(hres[t][r]);
  }
  stage_w_async<256>(W1t, Ws, tid);
  __syncthreads();
  gemm_tile_t<true>(X, Ws, wrow, l16, quad, acc);
  __syncthreads();
#pragma unroll
  for (int t = 0; t < 8; t++) {
    int col = t * 16 + l16; float bv = B1[col];
#pragma unroll
    for (int r = 0; r < 4; r++)
      X[(wrow + quad * 4 + r) * 136 + col] = f2h(fmaxf(acc[t][r] + bv, 0.f));
  }
  stage_w_async<256>(W2t, Ws, tid);
  __syncthreads();
  gemm_tile_t<true>(X, Ws, wrow, l16, quad, acc);
  __syncthreads();
#pragma unroll
  for (int t = 0; t < 8; t++) {
    int col = t * 16 + l16; float bv = B2[col];
#pragma unroll
    for (int r = 0; r < 4; r++)
      X[(wrow + quad * 4 + r) * 136 + col] = f2h(fmaxf(acc[t][r] + bv, 0.f));
  }
  stage_w_async<256>(W3t, Ws, tid);
  __syncthreads();
  gemm_tile_t<true>(X, Ws, wrow, l16, quad, acc);
  __syncthreads();
#pragma unroll
  for (int t = 0; t < 8; t++) {
    int col = t * 16 + l16; float bv = B3[col];
#pragma unroll
    for (int r = 0; r < 4; r++) {
      float v = hres[t][r] + acc[t][r] + bv;
      h[(size_t)(r0 + wrow + quad * 4 + r) * 128 + col] = f2h(v);
      if (do_qkv) X[(wrow + quad * 4 + r) * 136 + col] = f2h(v);
    }
  }
  if (!do_qkv) return;
  const _Float16* wts[5] = {Wqt, Wkt, Wvt, Wqk0, Wqk1};
  for (int w = 0; w < 5; w++) {
    __syncthreads();
    stage_w_async<256>(wts[w], Ws, tid);
    __syncthreads();
    gemm_tile_t<true>(X, Ws, wrow, l16, quad, acc);
#pragma unroll
    for (int t = 0; t < 8; t++) {
      int col = t * 16 + l16;
#pragma unroll
      for (int r = 0; r < 4; r++) {
        float v = acc[t][r];
        int rowg = r0 + wrow + quad * 4 + r;
        if (w < 3) {
          _Float16* C = (w == 0) ? qo : (w == 1) ? hko : hvo;
          C[(size_t)rowg * 128 + col] = f2h(v);
        } else {
          qkwo[(size_t)rowg * 256 + (w - 3) * 128 + col] = f2h(v);
        }
      }
    }
  }
}

// ---------------------------------------------------------------- fused edge + layer-0 QKV (block-range)
__global__ __launch_bounds__(256) void k_eq(const float* __restrict__ pos,
                                            const float* __restrict__ R,
                                            const int* __restrict__ nbr,
                                            _Float16* __restrict__ edge,
                                            const _Float16* __restrict__ A,
                                            const _Float16* __restrict__ Wqt,
                                            const _Float16* __restrict__ Wkt,
                                            const _Float16* __restrict__ Wvt,
                                            const _Float16* __restrict__ Wqk0,
                                            const _Float16* __restrict__ Wqk1,
                                            _Float16* __restrict__ q, _Float16* __restrict__ hk,
                                            _Float16* __restrict__ hv, _Float16* __restrict__ qkw) {
  __shared__ _Float16 X[64 * 136];
  __shared__ _Float16 Ws[128 * 128];
  int bb = blockIdx.x, tid = threadIdx.x;
  if (bb < EB) {
    // ---- edge features
    int idx = bb * 256 + tid;
    if (idx >= N_TOT * NNBR) return;
    int n = idx / NNBR;
    int m = nbr[idx];
    float dx = pos[m * 3 + 0] - pos[n * 3 + 0];
    float dy = pos[m * 3 + 1] - pos[n * 3 + 1];
    float dz = pos[m * 3 + 2] - pos[n * 3 + 2];
    float d = sqrtf(dx * dx + dy * dy + dz * dz);
    _Float16 eb[32];
#pragma unroll
    for (int j = 0; j < 16; j++) {
      float mu = (20.f / 15.f) * (float)j;
      float t = (d - mu) * 0.8f;
      eb[j] = f2h(__expf(-t * t));
    }
    float inv = 1.f / (d + 1e-8f);
    float ux = dx * inv, uy = dy * inv, uz = dz * inv;
    float Rn[9], Rm[9];
#pragma unroll
    for (int j = 0; j < 9; j++) { Rn[j] = R[(size_t)n * 9 + j]; Rm[j] = R[(size_t)m * 9 + j]; }
#pragma unroll
    for (int cc = 0; cc < 3; cc++)
      eb[16 + cc] = f2h(Rn[0 * 3 + cc] * ux + Rn[1 * 3 + cc] * uy + Rn[2 * 3 + cc] * uz);
#pragma unroll
    for (int cc = 0; cc < 3; cc++)
#pragma unroll
      for (int dd = 0; dd < 3; dd++)
        eb[19 + cc * 3 + dd] = f2h(Rn[0 * 3 + cc] * Rm[0 * 3 + dd] +
                                   Rn[1 * 3 + cc] * Rm[1 * 3 + dd] +
                                   Rn[2 * 3 + cc] * Rm[2 * 3 + dd]);
    eb[28] = f2h((float)(m - n));
    eb[29] = (_Float16)0.f; eb[30] = (_Float16)0.f; eb[31] = (_Float16)0.f;
    _Float16* e = edge + (size_t)idx * 32;
#pragma unroll
    for (int v = 0; v < 4; v++)
      *(uint4*)(e + v * 8) = *(const uint4*)(&eb[v * 8]);
  } else {
    // ---- layer-0 QKV (+qwk), round-4 geometry
    int r0 = (bb - EB) * 64;
    int lane = tid & 63, quad = lane >> 4, l16 = lane & 15, wrow = (tid >> 6) * 16;
    stage_x<256, 64>(A + (size_t)r0 * 128, X, tid, 128);
    const _Float16* wts[5] = {Wqt, Wkt, Wvt, Wqk0, Wqk1};
    f32x4 acc[8];
    for (int w = 0; w < 5; w++) {
      __syncthreads();
      stage_w_async<256>(wts[w], Ws, tid);
      __syncthreads();
      gemm_tile_t<true>(X, Ws, wrow, l16, quad, acc);
#pragma unroll
      for (int t = 0; t < 8; t++) {
        int col = t * 16 + l16;
#pragma unroll
        for (int r = 0; r < 4; r++) {
          float v = acc[t][r];
          int rowg = r0 + wrow + quad * 4 + r;
          if (w < 3) {
            _Float16* C = (w == 0) ? q : (w == 1) ? hk : hv;
            C[(size_t)rowg * 128 + col] = f2h(v);
          } else {
            qkw[(size_t)rowg * 256 + (w - 3) * 128 + col] = f2h(v);
          }
        }
      }
    }
  }
}

// ---------------------------------------------------------------- FUSED attn+post (parity-buffered) — one block = 64 rows
__global__ __launch_bounds__(256) void k_ap(
    const _Float16* __restrict__ q, const _Float16* __restrict__ hk,
    const _Float16* __restrict__ hv, const int* __restrict__ nbr,
    const _Float16* __restrict__ edge, const _Float16* __restrict__ qkw,
    _Float16* __restrict__ pe_g, _Float16* __restrict__ h,
    const _Float16* __restrict__ Wot, const _Float16* __restrict__ Wpe0,
    const _Float16* __restrict__ Wpe1,
    const _Float16* __restrict__ W1t, const float* __restrict__ B1,
    const _Float16* __restrict__ W2t, const float* __restrict__ B2,
    const _Float16* __restrict__ W3t, const float* __restrict__ B3,
    const _Float16* __restrict__ Wqt, const _Float16* __restrict__ Wkt,
    const _Float16* __restrict__ Wvt, const _Float16* __restrict__ Wqk0,
    const _Float16* __restrict__ Wqk1,
    _Float16* __restrict__ qo, _Float16* __restrict__ hko,
    _Float16* __restrict__ hvo, _Float16* __restrict__ qkwo, int do_qkv) {
  __shared__ _Float16 X[64 * 136];     // attn writes o here; post consumes it
  __shared__ _Float16 Ws[128 * 128];   // attn scratch aliased here pre-barrier
  int tid = threadIdx.x, wave = tid >> 6, lane = tid & 63;
  int r0 = blockIdx.x * 64;
  {
    // attn scratch inside Ws (17.9 KB of 64 KB): el | et | pl | nbl
    _Float16* el = Ws + wave * (15 * ELPH);                          // 4*600 f16 = 4800 B
    float* et = (float*)((char*)Ws + 4800) + wave * (32 * ETP);      // 4*640 f32 = 10240 B
    float* pl = (float*)((char*)Ws + 15040) + wave * (8 * PLP);      // 4*160 f32 = 2560 B
    int* nbl = (int*)((char*)Ws + 17600) + wave * 16;                // 4*16 int
    int c2 = lane * 2;
    if (lane < 32) et[lane * ETP + 15] = 0.f;
    int n0 = r0 + wave * 16;
#pragma unroll 1
    for (int ni = 0; ni < 16; ni++) {
      float ox, oy;
      attn_row(n0 + ni, lane, q, hk, hv, nbr, edge, qkw, pe_g,
               el, et, pl, nbl, ox, oy);
      *(f16x2*)&X[(wave * 16 + ni) * 136 + c2] = (f16x2){f2h(ox), f2h(oy)};
    }
  }
  __syncthreads();   // o in X complete; pe_g (this block's rows) drained; attn scratch dead
  post_body(pe_g, h, Wot, Wpe0, Wpe1, W1t, B1, W2t, B2, W3t, B3,
            Wqt, Wkt, Wvt, Wqk0, Wqk1, qo, hko, hvo, qkwo, do_qkv,
            X, Ws, tid, r0);
}

// ---------------------------------------------------------------- fallback: separate attn (round-9)
__global__ __launch_bounds__(256) void k_attn(const _Float16* __restrict__ q,
                                              const _Float16* __restrict__ hk,
                                              const _Float16* __restrict__ hv,
                                              const int* __restrict__ nbr,
                                              const _Float16* __restrict__ edge,
                                              const _Float16* __restrict__ qkw,
                                              _Float16* __restrict__ o,
                                              _Float16* __restrict__ pe_g) {
  __shared__ _Float16 elL[4][15 * ELPH];
  __shared__ float etL[4][32 * ETP];
  __shared__ float plL[4][8 * PLP];
  __shared__ int nbL[4][16];
  int tid = threadIdx.x, wave = tid >> 6, lane = tid & 63;
  _Float16* el = elL[wave]; float* et = etL[wave]; float* pl = plL[wave];
  int* nbl = nbL[wave];
  int c2 = lane * 2;
  if (lane < 32) et[lane * ETP + 15] = 0.f;
  int n0 = (blockIdx.x * 4 + wave) * APW;
#pragma unroll 1
  for (int ni = 0; ni < APW; ni++) {
    int n = n0 + ni;
    float ox, oy;
    attn_row(n, lane, q, hk, hv, nbr, edge, qkw, pe_g, el, et, pl, nbl, ox, oy);
    *(f16x2*)(o + (size_t)n * 128 + c2) = (f16x2){f2h(ox), f2h(oy)};
  }
}

// ---------------------------------------------------------------- fallback: separate post (round-9)
__global__ __launch_bounds__(256) void k_post(const _Float16* __restrict__ o,
                                              const _Float16* __restrict__ pe_g,
                                              _Float16* __restrict__ h,
                                              const _Float16* __restrict__ Wot,
                                              const _Float16* __restrict__ Wpe0,
                                              const _Float16* __restrict__ Wpe1,
                                              const _Float16* __restrict__ W1t, const float* __restrict__ B1,
                                              const _Float16* __restrict__ W2t, const float* __restrict__ B2,
                                              const _Float16* __restrict__ W3t, const float* __restrict__ B3,
                                              const _Float16* __restrict__ Wqt,
                                              const _Float16* __restrict__ Wkt,
                                              const _Float16* __restrict__ Wvt,
                                              const _Float16* __restrict__ Wqk0,
                                              const _Float16* __restrict__ Wqk1,
                                              _Float16* __restrict__ qo, _Float16* __restrict__ hko,
                                              _Float16* __restrict__ hvo, _Float16* __restrict__ qkwo,
                                              int do_qkv) {
  __shared__ _Float16 X[64 * 136];
  __shared__ _Float16 Ws[128 * 128];
  int tid = threadIdx.x, r0 = blockIdx.x * 64;
  stage_x<256, 64>(o + (size_t)r0 * 128, X, tid, 128);
  post_body(pe_g, h, Wot, Wpe0, Wpe1, W1t, B1, W2t, B2, W3t, B3,
            Wqt, Wkt, Wvt, Wqk0, Wqk1, qo, hko, hvo, qkwo, do_qkv,
            X, Ws, tid, r0);
}

// ---------------------------------------------------------------- MFMA conv+leaky+residual+maxpool2
__global__ __launch_bounds__(256) void k_convpool_m(const _Float16* __restrict__ x,
                                                    const _Float16* __restrict__ Wc,
                                                    const float* __restrict__ bias,
                                                    _Float16* __restrict__ outp, int Tin) {
  __shared__ _Float16 Xs[66 * 136];
  __shared__ _Float16 Ws[128 * 128];
  int tid = threadIdx.x;
  int b = blockIdx.y;
  int t0 = blockIdx.x * 64;
  for (int j = tid; j < 66 * 16; j += 256) {
    int row = j >> 4, seg = (j & 15) * 8;
    int t = t0 - 1 + row;
    uint4 v = {0u, 0u, 0u, 0u};
    if (t >= 0 && t < Tin) v = *(const uint4*)(x + ((size_t)b * Tin + t) * 128 + seg);
    *(uint4*)&Xs[row * 136 + seg] = v;
  }
  int lane = tid & 63, quad = lane >> 4, l16 = lane & 15, wrow = (tid >> 6) * 16;
  f32x4 acc[8];
#pragma unroll
  for (int t = 0; t < 8; t++) acc[t] = (f32x4){0.f, 0.f, 0.f, 0.f};
  for (int kt = 0; kt < 3; kt++) {
    __syncthreads();
    stage_w_async<256>(Wc + (size_t)kt * 16384, Ws, tid);
    __syncthreads();
#pragma unroll
    for (int kk = 0; kk < 4; kk++) {
      f16x8 a = *(const f16x8*)&Xs[(wrow + l16 + kt) * 136 + kk * 32 + quad * 8];
#pragma unroll
      for (int t = 0; t < 8; t++) {
        int rw = t * 16 + l16;
        f16x8 bfr = *(const f16x8*)&Ws[(rw << 7) + ((((kk << 2) + quad) ^ (rw & 7)) << 3)];
        acc[t] = __builtin_amdgcn_mfma_f32_16x16x32_f16(a, bfr, acc[t], 0, 0, 0);
      }
    }
  }
  int Tout = Tin >> 1;
#pragma unroll
  for (int t = 0; t < 8; t++) {
    int col = t * 16 + l16;
    float bv = bias[col];
#pragma unroll
    for (int rp = 0; rp < 2; rp++) {
      int rl0 = wrow + quad * 4 + rp * 2;
      float y0 = acc[t][rp * 2] + bv;
      float y1 = acc[t][rp * 2 + 1] + bv;
      float z0 = (float)Xs[(rl0 + 1) * 136 + col] + (y0 >= 0.f ? y0 : 0.01f * y0);
      float z1 = (float)Xs[(rl0 + 2) * 136 + col] + (y1 >= 0.f ? y1 : 0.01f * y1);
      outp[((size_t)b * Tout + ((t0 + rl0) >> 1)) * 128 + col] = f2h(fmaxf(z0, z1));
    }
  }
}

// ---------------------------------------------------------------- final reduce
__global__ __launch_bounds__(128) void k_final(const _Float16* __restrict__ x,
                                               const float* __restrict__ ew,
                                               const float* __restrict__ ebb,
                                               float* __restrict__ outp) {
  int b = blockIdx.x, cc = threadIdx.x;
  float s = 0.f;
#pragma unroll
  for (int t = 0; t < 32; t++) s += (float)x[((size_t)b * 32 + t) * 128 + cc];
  float v = s * ew[cc];
#pragma unroll
  for (int m = 1; m < 64; m <<= 1) v += __shfl_xor(v, m);
  __shared__ float red[2];
  if ((cc & 63) == 0) red[cc >> 6] = v;
  __syncthreads();
  if (cc == 0) outp[b] = red[0] + red[1] + ebb[0];
}

// ---------------------------------------------------------------- launch
extern "C" void kernel_launch(void* const* d_in, const int* in_sizes, int n_in,
                              void* d_out, int out_size, void* d_ws, size_t ws_size,
                              hipStream_t stream) {
  (void)in_sizes; (void)n_in; (void)out_size;
  const float* tert    = (const float*)d_in[0];
  const float* noise   = (const float*)d_in[3];
  const float* embed_w = (const float*)d_in[4];
  const float* embed_b = (const float*)d_in[5];
  const float* wq = (const float*)d_in[6];
  const float* wk = (const float*)d_in[7];
  const float* wv = (const float*)d_in[8];
  const float* wo = (const float*)d_in[9];
  const float* w1 = (const float*)d_in[10];
  const float* b1 = (const float*)d_in[11];
  const float* w2 = (const float*)d_in[12];
  const float* b2 = (const float*)d_in[13];
  const float* w3 = (const float*)d_in[14];
  const float* b3 = (const float*)d_in[15];
  const float* pw = (const float*)d_in[16];
  const float* pb = (const float*)d_in[17];
  const float* ew = (const float*)d_in[18];
  const float* eb = (const float*)d_in[19];
  float* outp = (float*)d_out;

  char* W = (char*)d_ws;
  float* pos  = (float*)W;        W += 393216;     // N*3 f32
  float* R    = (float*)W;        W += 1179648;    // N*9 f32
  int*   nbr  = (int*)W;          W += 1966080;    // N*15 i32
  _Float16* edge = (_Float16*)W;  W += 31457280;   // N*15*32 f16
  _Float16* h    = (_Float16*)W;  W += 8388608;    // N*128 f16
  _Float16* q    = (_Float16*)W;  W += 8388608;
  _Float16* hk   = (_Float16*)W;  W += 8388608;
  _Float16* hv   = (_Float16*)W;  W += 8388608;
  _Float16* o    = (_Float16*)W;  W += 8388608;
  _Float16* qkw_g = (_Float16*)W; W += 16777216;   // N*256 f16
  _Float16* pe_g  = (_Float16*)W; W += 16777216;   // N*256 f16
  _Float16* xa   = (_Float16*)W;  W += 4194304;    // B*256*128 f16
  _Float16* xb   = (_Float16*)W;  W += 2097152;    // B*128*128 f16
  _Float16* wbt  = (_Float16*)W;  W += 688128;     // 21*16384 f16
  _Float16* wqk  = (_Float16*)W;  W += 196608;     // 3*2*16384 f16
  _Float16* wpe  = (_Float16*)W;  W += 196608;     // 3*2*16384 f16
  _Float16* wct  = (_Float16*)W;  W += 393216;     // 12*16384 f16
  // parity-B buffers for fused attn+post (only used if workspace allows)
  _Float16* q2   = (_Float16*)W;  W += 8388608;
  _Float16* hk2  = (_Float16*)W;  W += 8388608;
  _Float16* hv2  = (_Float16*)W;  W += 8388608;
  _Float16* qkw2 = (_Float16*)W;  W += 16777216;
  size_t needed = (size_t)(W - (char*)d_ws);
  int fused = (ws_size >= needed) ? 1 : 0;

  k_pre<<<KNB + FRB + PRB, 256, 0, stream>>>(tert, noise, nbr, pos, R,
                                             wq, wk, wv, wo, w1, w2, w3, wbt,
                                             wqk, wpe, pw, wct, embed_w, embed_b, h);

  const _Float16* wt[3][7];
  for (int l = 0; l < 3; l++)
    for (int w = 0; w < 7; w++) wt[l][w] = wbt + (size_t)(l * 7 + w) * 16384;
  const _Float16* wqk_l[3][2];
  const _Float16* wpe_l[3][2];
  for (int l = 0; l < 3; l++)
    for (int bk = 0; bk < 2; bk++) {
      wqk_l[l][bk] = wqk + (size_t)(l * 2 + bk) * 16384;
      wpe_l[l][bk] = wpe + (size_t)(l * 2 + bk) * 16384;
    }

  k_eq<<<EB + 512, 256, 0, stream>>>(pos, R, nbr, edge,
                                     h, wt[0][0], wt[0][1], wt[0][2],
                                     wqk_l[0][0], wqk_l[0][1], q, hk, hv, qkw_g);

  if (fused) {
    for (int l = 0; l < 3; l++) {
      const _Float16 *qi, *hki, *hvi, *qkwi;
      _Float16 *qoB, *hkoB, *hvoB, *qkwoB;
      if (l & 1) { qi = q2; hki = hk2; hvi = hv2; qkwi = qkw2;
                   qoB = q; hkoB = hk; hvoB = hv; qkwoB = qkw_g; }
      else       { qi = q;  hki = hk;  hvi = hv;  qkwi = qkw_g;
                   qoB = q2; hkoB = hk2; hvoB = hv2; qkwoB = qkw2; }
      int nl = l + 1;
      int do_qkv = (nl < 3) ? 1 : 0;
      k_ap<<<512, 256, 0, stream>>>(qi, hki, hvi, nbr, edge, qkwi, pe_g, h,
                                    wt[l][3], wpe_l[l][0], wpe_l[l][1],
                                    wt[l][4], b1 + l * 128,
                                    wt[l][5], b2 + l * 128,
                                    wt[l][6], b3 + l * 128,
                                    do_qkv ? wt[nl][0] : wt[0][0],
                                    do_qkv ? wt[nl][1] : wt[0][1],
                                    do_qkv ? wt[nl][2] : wt[0][2],
                                    do_qkv ? wqk_l[nl][0] : wqk_l[0][0],
                                    do_qkv ? wqk_l[nl][1] : wqk_l[0][1],
                                    qoB, hkoB, hvoB, qkwoB, do_qkv);
    }
  } else {
    for (int l = 0; l < 3; l++) {
      k_attn<<<1024, 256, 0, stream>>>(q, hk, hv, nbr, edge, qkw_g, o, pe_g);
      int nl = l + 1;
      int do_qkv = (nl < 3) ? 1 : 0;
      k_post<<<512, 256, 0, stream>>>(o, pe_g, h, wt[l][3],
                                      wpe_l[l][0], wpe_l[l][1],
                                      wt[l][4], b1 + l * 128,
                                      wt[l][5], b2 + l * 128,
                                      wt[l][6], b3 + l * 128,
                                      do_qkv ? wt[nl][0] : wt[0][0],
                                      do_qkv ? wt[nl][1] : wt[0][1],
                                      do_qkv ? wt[nl][2] : wt[0][2],
                                      do_qkv ? wqk_l[nl][0] : wqk_l[0][0],
                                      do_qkv ? wqk_l[nl][1] : wqk_l[0][1],
                                      q, hk, hv, qkw_g, do_qkv);
    }
  }

  k_convpool_m<<<dim3(8, 64), 256, 0, stream>>>(h,  wct + 0 * 49152, pb + 0,   xa, 512);
  k_convpool_m<<<dim3(4, 64), 256, 0, stream>>>(xa, wct + 1 * 49152, pb + 128, xb, 256);
  k_convpool_m<<<dim3(2, 64), 256, 0, stream>>>(xb, wct + 2 * 49152, pb + 256, xa, 128);
  k_convpool_m<<<dim3(1, 64), 256, 0, stream>>>(xa, wct + 3 * 49152, pb + 384, xb, 64);
  k_final<<<64, 128, 0, stream>>>(xb, ew, eb, outp);
}

// Round 12
// 448.331 us; speedup vs baseline: 1.0292x; 1.0292x over previous
//
#include <hip/hip_runtime.h>
#include <math.h>

#define N_TOT 32768
#define NNBR 15
#define APW 8
#define ELPH 40
#define ETP 20
#define PLP 20

// k_pre block ranges
#define KNB 4096
#define FRB 128
#define PRB 3392

// k_eq block ranges
#define EB 1920

typedef __attribute__((ext_vector_type(8))) _Float16 f16x8;
typedef __attribute__((ext_vector_type(2))) _Float16 f16x2;
typedef __attribute__((ext_vector_type(4))) float f32x4;

#define CBAR() __asm__ volatile("" ::: "memory")
#define PAIR(v, c) __builtin_shufflevector(v, v, 2 * (c), 2 * (c) + 1)

__device__ __forceinline__ _Float16 f2h(float x) { return (_Float16)x; }

__device__ __forceinline__ float fdot2(f16x2 a, f16x2 b, float c) {
  float d;
  asm("v_dot2_f32_f16 %0, %1, %2, %3" : "=v"(d) : "v"(a), "v"(b), "v"(c));
  return d;
}

template <int CTRL>
__device__ __forceinline__ float dpp_mov_f32(float x) {
  return __int_as_float(
      __builtin_amdgcn_update_dpp(0, __float_as_int(x), CTRL, 0xf, 0xf, true));
}

template <int CTRL>
__device__ __forceinline__ unsigned dpp_max_u32(unsigned x) {
  unsigned y = (unsigned)__builtin_amdgcn_update_dpp(0, (int)x, CTRL, 0xf, 0xf, true);
  return y > x ? y : x;
}

template <int CTRL>
__device__ __forceinline__ unsigned long long dpp_max_u64(unsigned long long x) {
  unsigned lo = (unsigned)__builtin_amdgcn_update_dpp(
      0, (int)(unsigned)x, CTRL, 0xf, 0xf, true);
  unsigned hi = (unsigned)__builtin_amdgcn_update_dpp(
      0, (int)(unsigned)(x >> 32), CTRL, 0xf, 0xf, true);
  unsigned long long y = ((unsigned long long)hi << 32) | lo;
  return y > x ? y : x;
}

// top-3 insert, value-only strict compare; preserves j-ascending order on ties
__device__ __forceinline__ void ins3v(unsigned s, int j,
                                      unsigned& m1v, int& i1,
                                      unsigned& m2v, int& i2,
                                      unsigned& m3v, int& i3) {
  bool g1 = s > m1v;
  unsigned t = g1 ? m1v : s;  int it = g1 ? i1 : j;
  m1v = g1 ? s : m1v;         i1  = g1 ? j  : i1;
  bool g2 = t > m2v;
  unsigned u = g2 ? m2v : t;  int iu = g2 ? i2 : it;
  m2v = g2 ? t : m2v;         i2  = g2 ? it : i2;
  bool g3 = u > m3v;
  m3v = g3 ? u : m3v;         i3  = g3 ? iu : i3;
}

// ---------------------------------------------------------------- fused pre: kNN + frames + weight prep + hinit
__global__ __launch_bounds__(256) void k_pre(
    const float* __restrict__ tert, const float* __restrict__ noise,
    int* __restrict__ nbr, float* __restrict__ pos, float* __restrict__ R,
    const float* __restrict__ wq, const float* __restrict__ wk,
    const float* __restrict__ wv, const float* __restrict__ wo,
    const float* __restrict__ w1, const float* __restrict__ w2,
    const float* __restrict__ w3, _Float16* __restrict__ wbt,
    _Float16* __restrict__ wqk, _Float16* __restrict__ wpe,
    const float* __restrict__ pw, _Float16* __restrict__ wct,
    const float* __restrict__ ew, const float* __restrict__ ebias,
    _Float16* __restrict__ h) {
  __shared__ float posL[512 * 3];
  __shared__ float hvS[128];
  int bb = blockIdx.x, tid = threadIdx.x;
  if (bb < KNB) {
    // ---- kNN: 8 rows per block (2 per wave), 32-bit DPP select
    int b = bb >> 6;
    int n0 = b << 9;
    for (int i = tid; i < 1536; i += 256) {
      int r = i / 3, c = i - r * 3;
      posL[i] = tert[(size_t)(n0 + r) * 9 + 3 + c];
    }
    __syncthreads();
    int wave = tid >> 6, lane = tid & 63;
    int l = lane & 31;
    int rloc = (bb & 63) * 8 + wave * 2 + (lane >> 5);
    int row = n0 + rloc;
    const float* nrow = noise + (size_t)row * 512;
    float pix = posL[rloc * 3 + 0];
    float piy = posL[rloc * 3 + 1];
    float piz = posL[rloc * 3 + 2];
    unsigned m1v = 0u, m2v = 0u, m3v = 0u;
    int i1 = 0, i2 = 0, i3 = 0;
#pragma unroll
    for (int jj = 0; jj < 16; jj++) {
      int j = l + jj * 32;
      float dx = posL[j * 3 + 0] - pix;
      float dy = posL[j * 3 + 1] - piy;
      float dz = posL[j * 3 + 2] - piz;
      float c = -sqrtf(dx * dx + dy * dy + dz * dz) + 3.f * nrow[j];
      unsigned u = __float_as_uint(c);
      unsigned s = u ^ (unsigned)(((int)u >> 31) | (int)0x80000000);
      ins3v(s, j, m1v, i1, m2v, i2, m3v, i3);
    }
    int jmine = 0;
#pragma unroll 1
    for (int it = 0; it < NNBR; it++) {
      unsigned r = m1v;
      r = dpp_max_u32<0x111>(r);  // row_shr:1
      r = dpp_max_u32<0x112>(r);  // row_shr:2
      r = dpp_max_u32<0x114>(r);  // row_shr:4
      r = dpp_max_u32<0x118>(r);  // row_shr:8
      r = dpp_max_u32<0x142>(r);  // row_bcast:15 -> lanes 31/63 hold half-maxes
      unsigned gA = (unsigned)__builtin_amdgcn_readlane((int)r, 31);
      unsigned gB = (unsigned)__builtin_amdgcn_readlane((int)r, 63);
      unsigned gsel = (lane & 32) ? gB : gA;
      bool match = (m1v == gsel);
      unsigned long long mk = __ballot((int)match);
      unsigned mA = (unsigned)mk, mB = (unsigned)(mk >> 32);
      int jA = __builtin_amdgcn_readlane(i1, __ffs(mA) - 1);
      int jB = __builtin_amdgcn_readlane(i1, 31 + __ffs(mB));
      if (__popc(mA) > 1 || __popc(mB) > 1) {
        // rare exact tie-break: packed u64 reduce (value, 511-j)
        unsigned long long pk = ((unsigned long long)m1v << 9) | (unsigned)(511 - i1);
        pk = dpp_max_u64<0x111>(pk);
        pk = dpp_max_u64<0x112>(pk);
        pk = dpp_max_u64<0x114>(pk);
        pk = dpp_max_u64<0x118>(pk);
        pk = dpp_max_u64<0x142>(pk);
        unsigned pA = (unsigned)__builtin_amdgcn_readlane((int)(unsigned)pk, 31);
        unsigned pB = (unsigned)__builtin_amdgcn_readlane((int)(unsigned)pk, 63);
        if (__popc(mA) > 1) jA = 511 - (int)(pA & 511u);
        if (__popc(mB) > 1) jB = 511 - (int)(pB & 511u);
      }
      int j = (lane & 32) ? jB : jA;
      if (l == it) jmine = j;
      bool win = match && (i1 == j);
      if (win) { m1v = m2v; i1 = i2; m2v = m3v; i2 = i3; m3v = 0u; }
      // rare: winner exhausted its cached top-3 -> exact rescan below (value, index) threshold
      if (__any((int)(win && m1v == 0u))) {
        if (win && m1v == 0u) {
          unsigned gv = gsel; int gj = j;
          unsigned a1 = 0u, a2 = 0u, a3 = 0u;
          int b1i = 0, b2i = 0, b3i = 0;
#pragma unroll 1
          for (int jj = 0; jj < 16; jj++) {
            int j2 = l + jj * 32;
            float dx = posL[j2 * 3 + 0] - pix;
            float dy = posL[j2 * 3 + 1] - piy;
            float dz = posL[j2 * 3 + 2] - piz;
            float c = -sqrtf(dx * dx + dy * dy + dz * dz) + 3.f * nrow[j2];
            unsigned u = __float_as_uint(c);
            unsigned s = u ^ (unsigned)(((int)u >> 31) | (int)0x80000000);
            bool keep = (s < gv) || (s == gv && j2 > gj);
            ins3v(keep ? s : 0u, j2, a1, b1i, a2, b2i, a3, b3i);
          }
          m1v = a1; i1 = b1i; m2v = a2; i2 = b2i; m3v = a3; i3 = b3i;
        }
      }
    }
    if (l < NNBR) nbr[(size_t)row * NNBR + l] = n0 + jmine;
  } else if (bb < KNB + FRB) {
    // ---- frames
    int n = (bb - KNB) * 256 + tid;
    if (n >= N_TOT) return;
    float px = tert[n * 9 + 3], py = tert[n * 9 + 4], pz = tert[n * 9 + 5];
    pos[n * 3 + 0] = px; pos[n * 3 + 1] = py; pos[n * 3 + 2] = pz;
    int i0 = (n > 0) ? (n - 1) : 0;
    int i1 = (n < N_TOT - 1) ? n : (N_TOT - 2);
    float ax = tert[(i0 + 1) * 9 + 3] - tert[i0 * 9 + 3];
    float ay = tert[(i0 + 1) * 9 + 4] - tert[i0 * 9 + 4];
    float az = tert[(i0 + 1) * 9 + 5] - tert[i0 * 9 + 5];
    float il = 1.f / (sqrtf(ax * ax + ay * ay + az * az) + 1e-8f);
    float ux = ax * il, uy = ay * il, uz = az * il;
    float cx = tert[(i1 + 1) * 9 + 3] - tert[i1 * 9 + 3];
    float cy = tert[(i1 + 1) * 9 + 4] - tert[i1 * 9 + 4];
    float cz = tert[(i1 + 1) * 9 + 5] - tert[i1 * 9 + 5];
    il = 1.f / (sqrtf(cx * cx + cy * cy + cz * cz) + 1e-8f);
    float vx = cx * il, vy = cy * il, vz = cz * il;
    float bx = ux - vx, by = uy - vy, bz = uz - vz;
    il = 1.f / (sqrtf(bx * bx + by * by + bz * bz) + 1e-8f);
    bx *= il; by *= il; bz *= il;
    float nx = uy * vz - uz * vy;
    float ny = uz * vx - ux * vz;
    float nz = ux * vy - uy * vx;
    il = 1.f / (sqrtf(nx * nx + ny * ny + nz * nz) + 1e-8f);
    nx *= il; ny *= il; nz *= il;
    float ex = by * nz - bz * ny;
    float ey = bz * nx - bx * nz;
    float ez = bx * ny - by * nx;
    float* Rn = R + (size_t)n * 9;
    Rn[0] = bx; Rn[1] = nx; Rn[2] = ex;
    Rn[3] = by; Rn[4] = ny; Rn[5] = ey;
    Rn[6] = bz; Rn[7] = nz; Rn[8] = ez;
  } else {
    int pb2 = bb - (KNB + FRB);
    if (pb2 < 1344) {
      // ---- dense weight prep: fp32 [k][n] -> fp16 [n][k]
      int idx = pb2 * 256 + tid;
      int lL = idx / (7 * 16384);
      int r = idx % (7 * 16384);
      int w = r / 16384;
      int e = r % 16384;
      int k = e >> 7, n = e & 127;
      float val;
      switch (w) {
        case 0: val = wq[(size_t)lL * 16384 + e]; break;
        case 1: val = wk[(size_t)lL * 157 * 128 + e]; break;
        case 2: val = wv[(size_t)lL * 157 * 128 + e]; break;
        case 3: val = wo[(size_t)lL * 16384 + e]; break;
        case 4: val = w1[(size_t)lL * 16384 + e]; break;
        case 5: val = w2[(size_t)lL * 16384 + e]; break;
        default: val = w3[(size_t)lL * 16384 + e]; break;
      }
      wbt[(size_t)(lL * 7 + w) * 16384 + n * 128 + k] = f2h(val);
    } else if (pb2 < 1728) {
      // ---- Wqk composite (j = h*32+e layout)
      int idx = (pb2 - 1344) * 256 + tid;
      int lL = idx / 32768;
      int r = idx % 32768;
      int blk = r >> 14;
      int jp = (r >> 7) & 127;
      int c = r & 127;
      int j = blk * 128 + jp;
      int hh = j >> 5, e = j & 31;
      float val = 0.f;
      if (e < 29) {
        const float* wqp = wq + (size_t)lL * 16384 + (size_t)c * 128 + hh * 16;
        const float* wkp = wk + (size_t)lL * 157 * 128 + (size_t)(128 + e) * 128 + hh * 16;
        float s = 0.f;
#pragma unroll
        for (int d = 0; d < 16; d++) s = fmaf(wqp[d], wkp[d], s);
        val = 0.25f * s;
      }
      wqk[(size_t)idx] = f2h(val);
    } else if (pb2 < 2112) {
      // ---- wpe = Wv_e'' @ Wo (j = e*8+h layout)
      int idx = (pb2 - 1728) * 256 + tid;
      int lL = idx / 32768;
      int r = idx % 32768;
      int blk = r >> 14;
      int cout = (r >> 7) & 127;
      int jp = r & 127;
      int j = blk * 128 + jp;
      float val = 0.f;
      if (j < 232) {
        int e = j >> 3, hh = j & 7;
        const float* wvp = wv + (size_t)lL * 157 * 128 + (size_t)(128 + e) * 128 + hh * 16;
        const float* wop = wo + (size_t)lL * 16384 + (size_t)(hh * 16) * 128 + cout;
#pragma unroll
        for (int d = 0; d < 16; d++) val = fmaf(wvp[d], wop[d * 128], val);
      }
      wpe[(size_t)idx] = f2h(val);
    } else if (pb2 < 2880) {
      // ---- conv weight prep
      int idx = (pb2 - 2112) * 256 + tid;
      int kt = idx % 3;
      int rest = idx / 3;
      int i = rest % 128; rest /= 128;
      int oo = rest % 128;
      int s = rest / 128;
      wct[(((size_t)s * 3 + kt) * 128 + oo) * 128 + i] = f2h(pw[idx]);
    } else {
      // ---- h init (virtual grid of 512 blocks)
      int vb = pb2 - 2880;
      if (tid < 128) {
        float s = ebias[tid];
#pragma unroll
        for (int i = 0; i < 27; i++) s += ew[i * 128 + tid];
        hvS[tid] = s;
      }
      __syncthreads();
      size_t total = (size_t)N_TOT * 128;
      for (size_t j = (size_t)vb * 256 + tid; j < total; j += (size_t)512 * 256)
        h[j] = f2h(hvS[j & 127]);
    }
  }
}

// ---------------------------------------------------------------- GEMM helpers (round-4 geometry)
// Ws is LINEAR [128][128] f16, staged by global_load_lds with XOR-swizzled SOURCE;
// reads apply the same involution: chunk c -> c ^ (row & 7)  (chunk = 16B = 8 f16)
template <int NTHR>
__device__ __forceinline__ void stage_w_async(const _Float16* __restrict__ W,
                                              _Float16* Ws, int tid) {
  int wv = tid >> 6, lane = tid & 63;
  constexpr int ITERS = 16384 / (NTHR * 8);
#pragma unroll
  for (int it = 0; it < ITERS; it++) {
    int base = it * (NTHR * 8) + wv * 512;    // f16 units, wave-uniform
    int off = base + lane * 8;                // this lane's linear dest
    int row = off >> 7;
    int cL = (off >> 3) & 15;
    int cS = cL ^ (row & 7);
    const _Float16* src = W + ((size_t)row << 7) + (cS << 3);
    __builtin_amdgcn_global_load_lds(
        (const __attribute__((address_space(1))) void*)src,
        (__attribute__((address_space(3))) void*)(Ws + base), 16, 0, 0);
  }
}
template <int NTHR, int ROWS>
__device__ __forceinline__ void stage_x(const _Float16* __restrict__ src, _Float16* X,
                                        int tid, int rowstride) {
  for (int j = tid; j < ROWS * 16; j += NTHR) {
    int row = j >> 4, seg = (j & 15) * 8;
    *(uint4*)&X[row * 136 + seg] = *(const uint4*)(src + (size_t)row * rowstride + seg);
  }
}
template <bool RESET>
__device__ __forceinline__ void gemm_tile_t(const _Float16* X, const _Float16* Ws,
                                            int wrow, int l16, int quad, f32x4 acc[8]) {
  if (RESET) {
#pragma unroll
    for (int t = 0; t < 8; t++) acc[t] = (f32x4){0.f, 0.f, 0.f, 0.f};
  }
#pragma unroll
  for (int kk = 0; kk < 4; kk++) {
    f16x8 a = *(const f16x8*)&X[(wrow + l16) * 136 + kk * 32 + quad * 8];
#pragma unroll
    for (int t = 0; t < 8; t++) {
      int rw = t * 16 + l16;
      f16x8 b = *(const f16x8*)&Ws[(rw << 7) + ((((kk << 2) + quad) ^ (rw & 7)) << 3)];
      acc[t] = __builtin_amdgcn_mfma_f32_16x16x32_f16(a, b, acc[t], 0, 0, 0);
    }
  }
}

// ---------------------------------------------------------------- fused edge + layer-0 QKV (block-range)
__global__ __launch_bounds__(256) void k_eq(const float* __restrict__ pos,
                                            const float* __restrict__ R,
                                            const int* __restrict__ nbr,
                                            _Float16* __restrict__ edge,
                                            const _Float16* __restrict__ A,
                                            const _Float16* __restrict__ Wqt,
                                            const _Float16* __restrict__ Wkt,
                                            const _Float16* __restrict__ Wvt,
                                            const _Float16* __restrict__ Wqk0,
                                            const _Float16* __restrict__ Wqk1,
                                            _Float16* __restrict__ q, _Float16* __restrict__ hk,
                                            _Float16* __restrict__ hv, _Float16* __restrict__ qkw) {
  __shared__ _Float16 X[64 * 136];
  __shared__ _Float16 Ws[128 * 128];
  int bb = blockIdx.x, tid = threadIdx.x;
  if (bb < EB) {
    // ---- edge features
    int idx = bb * 256 + tid;
    if (idx >= N_TOT * NNBR) return;
    int n = idx / NNBR;
    int m = nbr[idx];
    float dx = pos[m * 3 + 0] - pos[n * 3 + 0];
    float dy = pos[m * 3 + 1] - pos[n * 3 + 1];
    float dz = pos[m * 3 + 2] - pos[n * 3 + 2];
    float d = sqrtf(dx * dx + dy * dy + dz * dz);
    _Float16 eb[32];
#pragma unroll
    for (int j = 0; j < 16; j++) {
      float mu = (20.f / 15.f) * (float)j;
      float t = (d - mu) * 0.8f;
      eb[j] = f2h(__expf(-t * t));
    }
    float inv = 1.f / (d + 1e-8f);
    float ux = dx * inv, uy = dy * inv, uz = dz * inv;
    float Rn[9], Rm[9];
#pragma unroll
    for (int j = 0; j < 9; j++) { Rn[j] = R[(size_t)n * 9 + j]; Rm[j] = R[(size_t)m * 9 + j]; }
#pragma unroll
    for (int cc = 0; cc < 3; cc++)
      eb[16 + cc] = f2h(Rn[0 * 3 + cc] * ux + Rn[1 * 3 + cc] * uy + Rn[2 * 3 + cc] * uz);
#pragma unroll
    for (int cc = 0; cc < 3; cc++)
#pragma unroll
      for (int dd = 0; dd < 3; dd++)
        eb[19 + cc * 3 + dd] = f2h(Rn[0 * 3 + cc] * Rm[0 * 3 + dd] +
                                   Rn[1 * 3 + cc] * Rm[1 * 3 + dd] +
                                   Rn[2 * 3 + cc] * Rm[2 * 3 + dd]);
    eb[28] = f2h((float)(m - n));
    eb[29] = (_Float16)0.f; eb[30] = (_Float16)0.f; eb[31] = (_Float16)0.f;
    _Float16* e = edge + (size_t)idx * 32;
#pragma unroll
    for (int v = 0; v < 4; v++)
      *(uint4*)(e + v * 8) = *(const uint4*)(&eb[v * 8]);
  } else {
    // ---- layer-0 QKV (+qwk), round-4 geometry
    int r0 = (bb - EB) * 64;
    int lane = tid & 63, quad = lane >> 4, l16 = lane & 15, wrow = (tid >> 6) * 16;
    stage_x<256, 64>(A + (size_t)r0 * 128, X, tid, 128);
    const _Float16* wts[5] = {Wqt, Wkt, Wvt, Wqk0, Wqk1};
    f32x4 acc[8];
    for (int w = 0; w < 5; w++) {
      __syncthreads();
      stage_w_async<256>(wts[w], Ws, tid);
      __syncthreads();
      gemm_tile_t<true>(X, Ws, wrow, l16, quad, acc);
#pragma unroll
      for (int t = 0; t < 8; t++) {
        int col = t * 16 + l16;
#pragma unroll
        for (int r = 0; r < 4; r++) {
          float v = acc[t][r];
          int rowg = r0 + wrow + quad * 4 + r;
          if (w < 3) {
            _Float16* C = (w == 0) ? q : (w == 1) ? hk : hv;
            C[(size_t)rowg * 128 + col] = f2h(v);
          } else {
            qkw[(size_t)rowg * 256 + (w - 3) * 128 + col] = f2h(v);
          }
        }
      }
    }
  }
}

// ---------------------------------------------------------------- fused o-proj(+pe) + residual + MLP (+ next QKV+qwk) — round-4 geometry
__global__ __launch_bounds__(256) void k_post(const _Float16* __restrict__ o,
                                              const _Float16* __restrict__ pe_g,
                                              _Float16* __restrict__ h,
                                              const _Float16* __restrict__ Wot,
                                              const _Float16* __restrict__ Wpe0,
                                              const _Float16* __restrict__ Wpe1,
                                              const _Float16* __restrict__ W1t, const float* __restrict__ B1,
                                              const _Float16* __restrict__ W2t, const float* __restrict__ B2,
                                              const _Float16* __restrict__ W3t, const float* __restrict__ B3,
                                              const _Float16* __restrict__ Wqt,
                                              const _Float16* __restrict__ Wkt,
                                              const _Float16* __restrict__ Wvt,
                                              const _Float16* __restrict__ Wqk0,
                                              const _Float16* __restrict__ Wqk1,
                                              _Float16* __restrict__ qo, _Float16* __restrict__ hko,
                                              _Float16* __restrict__ hvo, _Float16* __restrict__ qkwo,
                                              int do_qkv) {
  __shared__ _Float16 X[64 * 136];
  __shared__ _Float16 Ws[128 * 128];
  int tid = threadIdx.x, r0 = blockIdx.x * 64;
  int lane = tid & 63, quad = lane >> 4, l16 = lane & 15, wrow = (tid >> 6) * 16;
  f32x4 acc[8], hres[8];
  stage_x<256, 64>(o + (size_t)r0 * 128, X, tid, 128);
  stage_w_async<256>(Wot, Ws, tid);
  __syncthreads();
  gemm_tile_t<true>(X, Ws, wrow, l16, quad, acc);
  const _Float16* wpes[2] = {Wpe0, Wpe1};
#pragma unroll 1
  for (int blk = 0; blk < 2; blk++) {
    __syncthreads();
    stage_x<256, 64>(pe_g + (size_t)r0 * 256 + blk * 128, X, tid, 256);
    stage_w_async<256>(wpes[blk], Ws, tid);
    __syncthreads();
    gemm_tile_t<false>(X, Ws, wrow, l16, quad, acc);
  }
#pragma unroll
  for (int t = 0; t < 8; t++) {
    int col = t * 16 + l16;
#pragma unroll
    for (int r = 0; r < 4; r++)
      hres[t][r] = acc[t][r] + (float)h[(size_t)(r0 + wrow + quad * 4 + r) * 128 + col];
  }
  __syncthreads();
#pragma unroll
  for (int t = 0; t < 8; t++) {
    int col = t * 16 + l16;
#pragma unroll
    for (int r = 0; r < 4; r++)
      X[(wrow + quad * 4 + r) * 136 + col] = f2h(hres[t][r]);
  }
  stage_w_async<256>(W1t, Ws, tid);
  __syncthreads();
  gemm_tile_t<true>(X, Ws, wrow, l16, quad, acc);
  __syncthreads();
#pragma unroll
  for (int t = 0; t < 8; t++) {
    int col = t * 16 + l16; float bv = B1[col];
#pragma unroll
    for (int r = 0; r < 4; r++)
      X[(wrow + quad * 4 + r) * 136 + col] = f2h(fmaxf(acc[t][r] + bv, 0.f));
  }
  stage_w_async<256>(W2t, Ws, tid);
  __syncthreads();
  gemm_tile_t<true>(X, Ws, wrow, l16, quad, acc);
  __syncthreads();
#pragma unroll
  for (int t = 0; t < 8; t++) {
    int col = t * 16 + l16; float bv = B2[col];
#pragma unroll
    for (int r = 0; r < 4; r++)
      X[(wrow + quad * 4 + r) * 136 + col] = f2h(fmaxf(acc[t][r] + bv, 0.f));
  }
  stage_w_async<256>(W3t, Ws, tid);
  __syncthreads();
  gemm_tile_t<true>(X, Ws, wrow, l16, quad, acc);
  __syncthreads();
#pragma unroll
  for (int t = 0; t < 8; t++) {
    int col = t * 16 + l16; float bv = B3[col];
#pragma unroll
    for (int r = 0; r < 4; r++) {
      float v = hres[t][r] + acc[t][r] + bv;
      h[(size_t)(r0 + wrow + quad * 4 + r) * 128 + col] = f2h(v);
      if (do_qkv) X[(wrow + quad * 4 + r) * 136 + col] = f2h(v);
    }
  }
  if (!do_qkv) return;
  const _Float16* wts[5] = {Wqt, Wkt, Wvt, Wqk0, Wqk1};
  for (int w = 0; w < 5; w++) {
    __syncthreads();
    stage_w_async<256>(wts[w], Ws, tid);
    __syncthreads();
    gemm_tile_t<true>(X, Ws, wrow, l16, quad, acc);
#pragma unroll
    for (int t = 0; t < 8; t++) {
      int col = t * 16 + l16;
#pragma unroll
      for (int r = 0; r < 4; r++) {
        float v = acc[t][r];
        int rowg = r0 + wrow + quad * 4 + r;
        if (w < 3) {
          _Float16* C = (w == 0) ? qo : (w == 1) ? hko : hvo;
          C[(size_t)rowg * 128 + col] = f2h(v);
        } else {
          qkwo[(size_t)rowg * 256 + (w - 3) * 128 + col] = f2h(v);
        }
      }
    }
  }
}

// ---------------------------------------------------------------- attention core: fdot2 QK + wave-parallel softmax
__global__ __launch_bounds__(256) void k_attn(const _Float16* __restrict__ q,
                                              const _Float16* __restrict__ hk,
                                              const _Float16* __restrict__ hv,
                                              const int* __restrict__ nbr,
                                              const _Float16* __restrict__ edge,
                                              const _Float16* __restrict__ qkw,
                                              _Float16* __restrict__ o,
                                              _Float16* __restrict__ pe_g) {
  __shared__ _Float16 elL[4][15 * ELPH];
  __shared__ float etL[4][32 * ETP];
  __shared__ float plL[4][8 * PLP];
  __shared__ int nbL[4][16];
  int tid = threadIdx.x, wave = tid >> 6, lane = tid & 63;
  _Float16* el = elL[wave]; float* et = etL[wave]; float* pl = plL[wave];
  int* nbl = nbL[wave];
  int h8 = lane & 7, k2 = lane >> 3, c2 = lane * 2, h5 = lane >> 3;
  int kst = lane >> 2, gst = lane & 3;
  if (lane < 32) et[lane * ETP + 15] = 0.f;
  int n0 = (blockIdx.x * 4 + wave) * APW;
#pragma unroll 1
  for (int ni = 0; ni < APW; ni++) {
    int n = n0 + ni;
    if (lane < 60) {
      f16x8 ev = *(const f16x8*)(edge + ((size_t)n * 15 + kst) * 32 + gst * 8);
      *(f16x8*)&el[kst * ELPH + gst * 8] = ev;
      int ebs = gst * 8;
      et[(ebs + 0) * ETP + kst] = (float)ev[0];
      et[(ebs + 1) * ETP + kst] = (float)ev[1];
      et[(ebs + 2) * ETP + kst] = (float)ev[2];
      et[(ebs + 3) * ETP + kst] = (float)ev[3];
      et[(ebs + 4) * ETP + kst] = (float)ev[4];
      et[(ebs + 5) * ETP + kst] = (float)ev[5];
      et[(ebs + 6) * ETP + kst] = (float)ev[6];
      et[(ebs + 7) * ETP + kst] = (float)ev[7];
    }
    if (lane < 15) nbl[lane] = nbr[(size_t)n * NNBR + lane];
    const _Float16* qs = qkw + (size_t)n * 256 + h8 * 32;
    f16x8 w0 = *(const f16x8*)qs, w1 = *(const f16x8*)(qs + 8);
    f16x8 w2 = *(const f16x8*)(qs + 16), w3 = *(const f16x8*)(qs + 24);
    const _Float16* qp = q + (size_t)n * 128 + h8 * 16;
    f16x8 qa = *(const f16x8*)qp, qb = *(const f16x8*)(qp + 8);
    CBAR();
#pragma unroll
    for (int p = 0; p < 2; p++) {
      int k = k2 + p * 8;
      if (k < 15) {
        int m = nbl[k];
        const _Float16* hkp = hk + (size_t)m * 128 + h8 * 16;
        f16x8 ha = *(const f16x8*)hkp, hb = *(const f16x8*)(hkp + 8);
        float d0 = 0.f, d1 = 0.f;
        d0 = fdot2(PAIR(qa, 0), PAIR(ha, 0), d0);
        d1 = fdot2(PAIR(qa, 1), PAIR(ha, 1), d1);
        d0 = fdot2(PAIR(qa, 2), PAIR(ha, 2), d0);
        d1 = fdot2(PAIR(qa, 3), PAIR(ha, 3), d1);
        d0 = fdot2(PAIR(qb, 0), PAIR(hb, 0), d0);
        d1 = fdot2(PAIR(qb, 1), PAIR(hb, 1), d1);
        d0 = fdot2(PAIR(qb, 2), PAIR(hb, 2), d0);
        d1 = fdot2(PAIR(qb, 3), PAIR(hb, 3), d1);
        f16x8 l0 = *(const f16x8*)&el[k * ELPH + 0];
        f16x8 l1 = *(const f16x8*)&el[k * ELPH + 8];
        f16x8 l2 = *(const f16x8*)&el[k * ELPH + 16];
        f16x8 l3 = *(const f16x8*)&el[k * ELPH + 24];
        float e0 = 0.f, e1 = 0.f;
        e0 = fdot2(PAIR(l0, 0), PAIR(w0, 0), e0);
        e1 = fdot2(PAIR(l0, 1), PAIR(w0, 1), e1);
        e0 = fdot2(PAIR(l0, 2), PAIR(w0, 2), e0);
        e1 = fdot2(PAIR(l0, 3), PAIR(w0, 3), e1);
        e0 = fdot2(PAIR(l1, 0), PAIR(w1, 0), e0);
        e1 = fdot2(PAIR(l1, 1), PAIR(w1, 1), e1);
        e0 = fdot2(PAIR(l1, 2), PAIR(w1, 2), e0);
        e1 = fdot2(PAIR(l1, 3), PAIR(w1, 3), e1);
        e0 = fdot2(PAIR(l2, 0), PAIR(w2, 0), e0);
        e1 = fdot2(PAIR(l2, 1), PAIR(w2, 1), e1);
        e0 = fdot2(PAIR(l2, 2), PAIR(w2, 2), e0);
        e1 = fdot2(PAIR(l2, 3), PAIR(w2, 3), e1);
        e0 = fdot2(PAIR(l3, 0), PAIR(w3, 0), e0);
        e1 = fdot2(PAIR(l3, 1), PAIR(w3, 1), e1);
        e0 = fdot2(PAIR(l3, 2), PAIR(w3, 2), e0);
        e1 = fdot2(PAIR(l3, 3), PAIR(w3, 3), e1);
        pl[h8 * PLP + k] = fmaf(0.25f, d0 + d1, e0 + e1);
      } else {
        pl[h8 * PLP + 15] = -1e30f;
      }
    }
    CBAR();
    {
      // wave-parallel softmax: lane = (head hh, slot pair g / g+8)
      int hh = lane >> 3, g = lane & 7;
      float va = pl[hh * PLP + g];
      float vb = pl[hh * PLP + 8 + g];
      float mx = fmaxf(va, vb);
      mx = fmaxf(mx, dpp_mov_f32<0xB1>(mx));   // quad_perm xor1
      mx = fmaxf(mx, dpp_mov_f32<0x4E>(mx));   // quad_perm xor2
      mx = fmaxf(mx, dpp_mov_f32<0x141>(mx));  // row_half_mirror (xor4 in 8-group)
      float ea = __expf(va - mx), eb = __expf(vb - mx);
      float s = ea + eb;
      s += dpp_mov_f32<0xB1>(s);
      s += dpp_mov_f32<0x4E>(s);
      s += dpp_mov_f32<0x141>(s);
      float inv = 1.f / s;
      pl[hh * PLP + g] = ea * inv;
      pl[hh * PLP + 8 + g] = eb * inv;
    }
    CBAR();
    _Float16* peo = pe_g + (size_t)n * 256;
#pragma unroll
    for (int p = 0; p < 4; p++) {
      int j = p * 64 + lane;
      float s = 0.f;
      if (j < 232) {
        int e = j >> 3, hh = j & 7;
        f32x4 p0 = *(const f32x4*)&pl[hh * PLP + 0];
        f32x4 p1 = *(const f32x4*)&pl[hh * PLP + 4];
        f32x4 p2 = *(const f32x4*)&pl[hh * PLP + 8];
        f32x4 p3 = *(const f32x4*)&pl[hh * PLP + 12];
        f32x4 t0 = *(const f32x4*)&et[e * ETP + 0];
        f32x4 t1 = *(const f32x4*)&et[e * ETP + 4];
        f32x4 t2 = *(const f32x4*)&et[e * ETP + 8];
        f32x4 t3 = *(const f32x4*)&et[e * ETP + 12];
        s = p0[0]*t0[0] + p0[1]*t0[1] + p0[2]*t0[2] + p0[3]*t0[3]
          + p1[0]*t1[0] + p1[1]*t1[1] + p1[2]*t1[2] + p1[3]*t1[3]
          + p2[0]*t2[0] + p2[1]*t2[1] + p2[2]*t2[2] + p2[3]*t2[3]
          + p3[0]*t3[0] + p3[1]*t3[1] + p3[2]*t3[2] + p3[3]*t3[3];
      }
      peo[j] = f2h(s);
    }
    float pk[16];
    *(f32x4*)&pk[0]  = *(const f32x4*)&pl[h5 * PLP + 0];
    *(f32x4*)&pk[4]  = *(const f32x4*)&pl[h5 * PLP + 4];
    *(f32x4*)&pk[8]  = *(const f32x4*)&pl[h5 * PLP + 8];
    *(f32x4*)&pk[12] = *(const f32x4*)&pl[h5 * PLP + 12];
    float ox = 0.f, oy = 0.f;
#pragma unroll
    for (int k = 0; k < 15; k++) {
      int m = nbl[k];
      f16x2 hh = *(const f16x2*)(hv + (size_t)m * 128 + c2);
      ox = fmaf(pk[k], (float)hh[0], ox);
      oy = fmaf(pk[k], (float)hh[1], oy);
    }
    *(f16x2*)(o + (size_t)n * 128 + c2) = (f16x2){f2h(ox), f2h(oy)};
    CBAR();
  }
}

// ---------------------------------------------------------------- MFMA conv+leaky+residual+maxpool2 (round-4)
__global__ __launch_bounds__(256) void k_convpool_m(const _Float16* __restrict__ x,
                                                    const _Float16* __restrict__ Wc,
                                                    const float* __restrict__ bias,
                                                    _Float16* __restrict__ outp, int Tin) {
  __shared__ _Float16 Xs[66 * 136];
  __shared__ _Float16 Ws[128 * 128];
  int tid = threadIdx.x;
  int b = blockIdx.y;
  int t0 = blockIdx.x * 64;
  for (int j = tid; j < 66 * 16; j += 256) {
    int row = j >> 4, seg = (j & 15) * 8;
    int t = t0 - 1 + row;
    uint4 v = {0u, 0u, 0u, 0u};
    if (t >= 0 && t < Tin) v = *(const uint4*)(x + ((size_t)b * Tin + t) * 128 + seg);
    *(uint4*)&Xs[row * 136 + seg] = v;
  }
  int lane = tid & 63, quad = lane >> 4, l16 = lane & 15, wrow = (tid >> 6) * 16;
  f32x4 acc[8];
#pragma unroll
  for (int t = 0; t < 8; t++) acc[t] = (f32x4){0.f, 0.f, 0.f, 0.f};
  for (int kt = 0; kt < 3; kt++) {
    __syncthreads();
    stage_w_async<256>(Wc + (size_t)kt * 16384, Ws, tid);
    __syncthreads();
#pragma unroll
    for (int kk = 0; kk < 4; kk++) {
      f16x8 a = *(const f16x8*)&Xs[(wrow + l16 + kt) * 136 + kk * 32 + quad * 8];
#pragma unroll
      for (int t = 0; t < 8; t++) {
        int rw = t * 16 + l16;
        f16x8 bfr = *(const f16x8*)&Ws[(rw << 7) + ((((kk << 2) + quad) ^ (rw & 7)) << 3)];
        acc[t] = __builtin_amdgcn_mfma_f32_16x16x32_f16(a, bfr, acc[t], 0, 0, 0);
      }
    }
  }
  int Tout = Tin >> 1;
#pragma unroll
  for (int t = 0; t < 8; t++) {
    int col = t * 16 + l16;
    float bv = bias[col];
#pragma unroll
    for (int rp = 0; rp < 2; rp++) {
      int rl0 = wrow + quad * 4 + rp * 2;
      float y0 = acc[t][rp * 2] + bv;
      float y1 = acc[t][rp * 2 + 1] + bv;
      float z0 = (float)Xs[(rl0 + 1) * 136 + col] + (y0 >= 0.f ? y0 : 0.01f * y0);
      float z1 = (float)Xs[(rl0 + 2) * 136 + col] + (y1 >= 0.f ? y1 : 0.01f * y1);
      outp[((size_t)b * Tout + ((t0 + rl0) >> 1)) * 128 + col] = f2h(fmaxf(z0, z1));
    }
  }
}

// ---------------------------------------------------------------- final reduce (round-4)
__global__ __launch_bounds__(128) void k_final(const _Float16* __restrict__ x,
                                               const float* __restrict__ ew,
                                               const float* __restrict__ ebb,
                                               float* __restrict__ outp) {
  int b = blockIdx.x, cc = threadIdx.x;
  float s = 0.f;
#pragma unroll
  for (int t = 0; t < 32; t++) s += (float)x[((size_t)b * 32 + t) * 128 + cc];
  float v = s * ew[cc];
#pragma unroll
  for (int m = 1; m < 64; m <<= 1) v += __shfl_xor(v, m);
  __shared__ float red[2];
  if ((cc & 63) == 0) red[cc >> 6] = v;
  __syncthreads();
  if (cc == 0) outp[b] = red[0] + red[1] + ebb[0];
}

// ---------------------------------------------------------------- launch
extern "C" void kernel_launch(void* const* d_in, const int* in_sizes, int n_in,
                              void* d_out, int out_size, void* d_ws, size_t ws_size,
                              hipStream_t stream) {
  (void)in_sizes; (void)n_in; (void)out_size; (void)ws_size;
  const float* tert    = (const float*)d_in[0];
  const float* noise   = (const float*)d_in[3];
  const float* embed_w = (const float*)d_in[4];
  const float* embed_b = (const float*)d_in[5];
  const float* wq = (const float*)d_in[6];
  const float* wk = (const float*)d_in[7];
  const float* wv = (const float*)d_in[8];
  const float* wo = (const float*)d_in[9];
  const float* w1 = (const float*)d_in[10];
  const float* b1 = (const float*)d_in[11];
  const float* w2 = (const float*)d_in[12];
  const float* b2 = (const float*)d_in[13];
  const float* w3 = (const float*)d_in[14];
  const float* b3 = (const float*)d_in[15];
  const float* pw = (const float*)d_in[16];
  const float* pb = (const float*)d_in[17];
  const float* ew = (const float*)d_in[18];
  const float* eb = (const float*)d_in[19];
  float* outp = (float*)d_out;

  char* W = (char*)d_ws;
  float* pos  = (float*)W;        W += 393216;     // N*3 f32
  float* R    = (float*)W;        W += 1179648;    // N*9 f32
  int*   nbr  = (int*)W;          W += 1966080;    // N*15 i32
  _Float16* edge = (_Float16*)W;  W += 31457280;   // N*15*32 f16
  _Float16* h    = (_Float16*)W;  W += 8388608;    // N*128 f16
  _Float16* q    = (_Float16*)W;  W += 8388608;
  _Float16* hk   = (_Float16*)W;  W += 8388608;
  _Float16* hv   = (_Float16*)W;  W += 8388608;
  _Float16* o    = (_Float16*)W;  W += 8388608;
  _Float16* qkw_g = (_Float16*)W; W += 16777216;   // N*256 f16
  _Float16* pe_g  = (_Float16*)W; W += 16777216;   // N*256 f16
  _Float16* xa   = (_Float16*)W;  W += 4194304;    // B*256*128 f16
  _Float16* xb   = (_Float16*)W;  W += 2097152;    // B*128*128 f16
  _Float16* wbt  = (_Float16*)W;  W += 688128;     // 21*16384 f16
  _Float16* wqk  = (_Float16*)W;  W += 196608;     // 3*2*16384 f16
  _Float16* wpe  = (_Float16*)W;  W += 196608;     // 3*2*16384 f16
  _Float16* wct  = (_Float16*)W;  W += 393216;     // 12*16384 f16

  k_pre<<<KNB + FRB + PRB, 256, 0, stream>>>(tert, noise, nbr, pos, R,
                                             wq, wk, wv, wo, w1, w2, w3, wbt,
                                             wqk, wpe, pw, wct, embed_w, embed_b, h);

  const _Float16* wt[3][7];
  for (int l = 0; l < 3; l++)
    for (int w = 0; w < 7; w++) wt[l][w] = wbt + (size_t)(l * 7 + w) * 16384;
  const _Float16* wqk_l[3][2];
  const _Float16* wpe_l[3][2];
  for (int l = 0; l < 3; l++)
    for (int bk = 0; bk < 2; bk++) {
      wqk_l[l][bk] = wqk + (size_t)(l * 2 + bk) * 16384;
      wpe_l[l][bk] = wpe + (size_t)(l * 2 + bk) * 16384;
    }

  k_eq<<<EB + 512, 256, 0, stream>>>(pos, R, nbr, edge,
                                     h, wt[0][0], wt[0][1], wt[0][2],
                                     wqk_l[0][0], wqk_l[0][1], q, hk, hv, qkw_g);
  for (int l = 0; l < 3; l++) {
    k_attn<<<1024, 256, 0, stream>>>(q, hk, hv, nbr, edge, qkw_g, o, pe_g);
    int nl = l + 1;
    int do_qkv = (nl < 3) ? 1 : 0;
    k_post<<<512, 256, 0, stream>>>(o, pe_g, h, wt[l][3],
                                    wpe_l[l][0], wpe_l[l][1],
                                    wt[l][4], b1 + l * 128,
                                    wt[l][5], b2 + l * 128,
                                    wt[l][6], b3 + l * 128,
                                    do_qkv ? wt[nl][0] : nullptr,
                                    do_qkv ? wt[nl][1] : nullptr,
                                    do_qkv ? wt[nl][2] : nullptr,
                                    do_qkv ? wqk_l[nl][0] : nullptr,
                                    do_qkv ? wqk_l[nl][1] : nullptr,
                                    q, hk, hv, qkw_g, do_qkv);
  }

  k_convpool_m<<<dim3(8, 64), 256, 0, stream>>>(h,  wct + 0 * 49152, pb + 0,   xa, 512);
  k_convpool_m<<<dim3(4, 64), 256, 0, stream>>>(xa, wct + 1 * 49152, pb + 128, xb, 256);
  k_convpool_m<<<dim3(2, 64), 256, 0, stream>>>(xb, wct + 2 * 49152, pb + 256, xa, 128);
  k_convpool_m<<<dim3(1, 64), 256, 0, stream>>>(xa, wct + 3 * 49152, pb + 384, xb, 64);
  k_final<<<64, 128, 0, stream>>>(xb, ew, eb, outp);
}

// Round 13
// 447.320 us; speedup vs baseline: 1.0316x; 1.0023x over previous
//
#include <hip/hip_runtime.h>
#include <math.h>

#define N_TOT 32768
#define NNBR 15
#define APW 8
#define ELPH 40
#define ETP 20
#define PLP 20

// k_pre block ranges
#define KNB 4096
#define FRB 128
#define PRB 3392

// k_eq block ranges
#define EB 1920

typedef __attribute__((ext_vector_type(8))) _Float16 f16x8;
typedef __attribute__((ext_vector_type(2))) _Float16 f16x2;
typedef __attribute__((ext_vector_type(4))) float f32x4;

#define CBAR() __asm__ volatile("" ::: "memory")
#define PAIR(v, c) __builtin_shufflevector(v, v, 2 * (c), 2 * (c) + 1)

__device__ __forceinline__ _Float16 f2h(float x) { return (_Float16)x; }

__device__ __forceinline__ float fdot2(f16x2 a, f16x2 b, float c) {
  float d;
  asm("v_dot2_f32_f16 %0, %1, %2, %3" : "=v"(d) : "v"(a), "v"(b), "v"(c));
  return d;
}

template <int CTRL>
__device__ __forceinline__ float dpp_mov_f32(float x) {
  return __int_as_float(
      __builtin_amdgcn_update_dpp(0, __float_as_int(x), CTRL, 0xf, 0xf, true));
}

template <int CTRL>
__device__ __forceinline__ unsigned dpp_max_u32(unsigned x) {
  unsigned y = (unsigned)__builtin_amdgcn_update_dpp(0, (int)x, CTRL, 0xf, 0xf, true);
  return y > x ? y : x;
}

template <int CTRL>
__device__ __forceinline__ unsigned long long dpp_max_u64(unsigned long long x) {
  unsigned lo = (unsigned)__builtin_amdgcn_update_dpp(
      0, (int)(unsigned)x, CTRL, 0xf, 0xf, true);
  unsigned hi = (unsigned)__builtin_amdgcn_update_dpp(
      0, (int)(unsigned)(x >> 32), CTRL, 0xf, 0xf, true);
  unsigned long long y = ((unsigned long long)hi << 32) | lo;
  return y > x ? y : x;
}

// top-3 insert, value-only strict compare; preserves j-ascending order on ties
__device__ __forceinline__ void ins3v(unsigned s, int j,
                                      unsigned& m1v, int& i1,
                                      unsigned& m2v, int& i2,
                                      unsigned& m3v, int& i3) {
  bool g1 = s > m1v;
  unsigned t = g1 ? m1v : s;  int it = g1 ? i1 : j;
  m1v = g1 ? s : m1v;         i1  = g1 ? j  : i1;
  bool g2 = t > m2v;
  unsigned u = g2 ? m2v : t;  int iu = g2 ? i2 : it;
  m2v = g2 ? t : m2v;         i2  = g2 ? it : i2;
  bool g3 = u > m3v;
  m3v = g3 ? u : m3v;         i3  = g3 ? iu : i3;
}

// ---------------------------------------------------------------- fused pre: kNN + frames + weight prep + hinit
__global__ __launch_bounds__(256) void k_pre(
    const float* __restrict__ tert, const float* __restrict__ noise,
    int* __restrict__ nbr, float* __restrict__ pos, float* __restrict__ R,
    const float* __restrict__ wq, const float* __restrict__ wk,
    const float* __restrict__ wv, const float* __restrict__ wo,
    const float* __restrict__ w1, const float* __restrict__ w2,
    const float* __restrict__ w3, _Float16* __restrict__ wbt,
    _Float16* __restrict__ wqk, _Float16* __restrict__ wpe,
    const float* __restrict__ pw, _Float16* __restrict__ wct,
    const float* __restrict__ ew, const float* __restrict__ ebias,
    _Float16* __restrict__ h) {
  __shared__ float posL4[512 * 4];
  __shared__ float hvS[128];
  int bb = blockIdx.x, tid = threadIdx.x;
  if (bb < KNB) {
    // ---- kNN: 8 rows per block (2 per wave), 32-bit DPP select, float4 pos tile
    int b = bb >> 6;
    int n0 = b << 9;
    for (int i = tid; i < 2048; i += 256) {
      int r = i >> 2, c = i & 3;
      posL4[i] = (c < 3) ? tert[(size_t)(n0 + r) * 9 + 3 + c] : 0.f;
    }
    __syncthreads();
    int wave = tid >> 6, lane = tid & 63;
    int l = lane & 31;
    int rloc = (bb & 63) * 8 + wave * 2 + (lane >> 5);
    int row = n0 + rloc;
    const float* nrow = noise + (size_t)row * 512;
    float pix = posL4[rloc * 4 + 0];
    float piy = posL4[rloc * 4 + 1];
    float piz = posL4[rloc * 4 + 2];
    unsigned m1v = 0u, m2v = 0u, m3v = 0u;
    int i1 = 0, i2 = 0, i3 = 0;
#pragma unroll
    for (int jj = 0; jj < 16; jj++) {
      int j = l + jj * 32;
      f32x4 pj = *(const f32x4*)&posL4[j << 2];
      float dx = pj[0] - pix;
      float dy = pj[1] - piy;
      float dz = pj[2] - piz;
      float c = -sqrtf(dx * dx + dy * dy + dz * dz) + 3.f * nrow[j];
      unsigned u = __float_as_uint(c);
      unsigned s = u ^ (unsigned)(((int)u >> 31) | (int)0x80000000);
      ins3v(s, j, m1v, i1, m2v, i2, m3v, i3);
    }
    int jmine = 0;
#pragma unroll 1
    for (int it = 0; it < NNBR; it++) {
      unsigned r = m1v;
      r = dpp_max_u32<0x111>(r);  // row_shr:1
      r = dpp_max_u32<0x112>(r);  // row_shr:2
      r = dpp_max_u32<0x114>(r);  // row_shr:4
      r = dpp_max_u32<0x118>(r);  // row_shr:8
      r = dpp_max_u32<0x142>(r);  // row_bcast:15 -> lanes 31/63 hold half-maxes
      unsigned gA = (unsigned)__builtin_amdgcn_readlane((int)r, 31);
      unsigned gB = (unsigned)__builtin_amdgcn_readlane((int)r, 63);
      unsigned gsel = (lane & 32) ? gB : gA;
      bool match = (m1v == gsel);
      unsigned long long mk = __ballot((int)match);
      unsigned mA = (unsigned)mk, mB = (unsigned)(mk >> 32);
      int jA = __builtin_amdgcn_readlane(i1, __ffs(mA) - 1);
      int jB = __builtin_amdgcn_readlane(i1, 31 + __ffs(mB));
      if (__popc(mA) > 1 || __popc(mB) > 1) {
        // rare exact tie-break: packed u64 reduce (value, 511-j)
        unsigned long long pk = ((unsigned long long)m1v << 9) | (unsigned)(511 - i1);
        pk = dpp_max_u64<0x111>(pk);
        pk = dpp_max_u64<0x112>(pk);
        pk = dpp_max_u64<0x114>(pk);
        pk = dpp_max_u64<0x118>(pk);
        pk = dpp_max_u64<0x142>(pk);
        unsigned pA = (unsigned)__builtin_amdgcn_readlane((int)(unsigned)pk, 31);
        unsigned pB = (unsigned)__builtin_amdgcn_readlane((int)(unsigned)pk, 63);
        if (__popc(mA) > 1) jA = 511 - (int)(pA & 511u);
        if (__popc(mB) > 1) jB = 511 - (int)(pB & 511u);
      }
      int j = (lane & 32) ? jB : jA;
      if (l == it) jmine = j;
      bool win = match && (i1 == j);
      if (win) { m1v = m2v; i1 = i2; m2v = m3v; i2 = i3; m3v = 0u; }
      // rare: winner exhausted its cached top-3 -> exact rescan below (value, index) threshold
      if (__any((int)(win && m1v == 0u))) {
        if (win && m1v == 0u) {
          unsigned gv = gsel; int gj = j;
          unsigned a1 = 0u, a2 = 0u, a3 = 0u;
          int b1i = 0, b2i = 0, b3i = 0;
#pragma unroll 1
          for (int jj = 0; jj < 16; jj++) {
            int j2 = l + jj * 32;
            f32x4 pj = *(const f32x4*)&posL4[j2 << 2];
            float dx = pj[0] - pix;
            float dy = pj[1] - piy;
            float dz = pj[2] - piz;
            float c = -sqrtf(dx * dx + dy * dy + dz * dz) + 3.f * nrow[j2];
            unsigned u = __float_as_uint(c);
            unsigned s = u ^ (unsigned)(((int)u >> 31) | (int)0x80000000);
            bool keep = (s < gv) || (s == gv && j2 > gj);
            ins3v(keep ? s : 0u, j2, a1, b1i, a2, b2i, a3, b3i);
          }
          m1v = a1; i1 = b1i; m2v = a2; i2 = b2i; m3v = a3; i3 = b3i;
        }
      }
    }
    if (l < NNBR) nbr[(size_t)row * NNBR + l] = n0 + jmine;
  } else if (bb < KNB + FRB) {
    // ---- frames
    int n = (bb - KNB) * 256 + tid;
    if (n >= N_TOT) return;
    float px = tert[n * 9 + 3], py = tert[n * 9 + 4], pz = tert[n * 9 + 5];
    pos[n * 3 + 0] = px; pos[n * 3 + 1] = py; pos[n * 3 + 2] = pz;
    int i0 = (n > 0) ? (n - 1) : 0;
    int i1 = (n < N_TOT - 1) ? n : (N_TOT - 2);
    float ax = tert[(i0 + 1) * 9 + 3] - tert[i0 * 9 + 3];
    float ay = tert[(i0 + 1) * 9 + 4] - tert[i0 * 9 + 4];
    float az = tert[(i0 + 1) * 9 + 5] - tert[i0 * 9 + 5];
    float il = 1.f / (sqrtf(ax * ax + ay * ay + az * az) + 1e-8f);
    float ux = ax * il, uy = ay * il, uz = az * il;
    float cx = tert[(i1 + 1) * 9 + 3] - tert[i1 * 9 + 3];
    float cy = tert[(i1 + 1) * 9 + 4] - tert[i1 * 9 + 4];
    float cz = tert[(i1 + 1) * 9 + 5] - tert[i1 * 9 + 5];
    il = 1.f / (sqrtf(cx * cx + cy * cy + cz * cz) + 1e-8f);
    float vx = cx * il, vy = cy * il, vz = cz * il;
    float bx = ux - vx, by = uy - vy, bz = uz - vz;
    il = 1.f / (sqrtf(bx * bx + by * by + bz * bz) + 1e-8f);
    bx *= il; by *= il; bz *= il;
    float nx = uy * vz - uz * vy;
    float ny = uz * vx - ux * vz;
    float nz = ux * vy - uy * vx;
    il = 1.f / (sqrtf(nx * nx + ny * ny + nz * nz) + 1e-8f);
    nx *= il; ny *= il; nz *= il;
    float ex = by * nz - bz * ny;
    float ey = bz * nx - bx * nz;
    float ez = bx * ny - by * nx;
    float* Rn = R + (size_t)n * 9;
    Rn[0] = bx; Rn[1] = nx; Rn[2] = ex;
    Rn[3] = by; Rn[4] = ny; Rn[5] = ey;
    Rn[6] = bz; Rn[7] = nz; Rn[8] = ez;
  } else {
    int pb2 = bb - (KNB + FRB);
    if (pb2 < 1344) {
      // ---- dense weight prep: fp32 [k][n] -> fp16 [n][k]
      int idx = pb2 * 256 + tid;
      int lL = idx / (7 * 16384);
      int r = idx % (7 * 16384);
      int w = r / 16384;
      int e = r % 16384;
      int k = e >> 7, n = e & 127;
      float val;
      switch (w) {
        case 0: val = wq[(size_t)lL * 16384 + e]; break;
        case 1: val = wk[(size_t)lL * 157 * 128 + e]; break;
        case 2: val = wv[(size_t)lL * 157 * 128 + e]; break;
        case 3: val = wo[(size_t)lL * 16384 + e]; break;
        case 4: val = w1[(size_t)lL * 16384 + e]; break;
        case 5: val = w2[(size_t)lL * 16384 + e]; break;
        default: val = w3[(size_t)lL * 16384 + e]; break;
      }
      wbt[(size_t)(lL * 7 + w) * 16384 + n * 128 + k] = f2h(val);
    } else if (pb2 < 1728) {
      // ---- Wqk composite (j = h*32+e layout)
      int idx = (pb2 - 1344) * 256 + tid;
      int lL = idx / 32768;
      int r = idx % 32768;
      int blk = r >> 14;
      int jp = (r >> 7) & 127;
      int c = r & 127;
      int j = blk * 128 + jp;
      int hh = j >> 5, e = j & 31;
      float val = 0.f;
      if (e < 29) {
        const float* wqp = wq + (size_t)lL * 16384 + (size_t)c * 128 + hh * 16;
        const float* wkp = wk + (size_t)lL * 157 * 128 + (size_t)(128 + e) * 128 + hh * 16;
        float s = 0.f;
#pragma unroll
        for (int d = 0; d < 16; d++) s = fmaf(wqp[d], wkp[d], s);
        val = 0.25f * s;
      }
      wqk[(size_t)idx] = f2h(val);
    } else if (pb2 < 2112) {
      // ---- wpe = Wv_e'' @ Wo (j = e*8+h layout)
      int idx = (pb2 - 1728) * 256 + tid;
      int lL = idx / 32768;
      int r = idx % 32768;
      int blk = r >> 14;
      int cout = (r >> 7) & 127;
      int jp = r & 127;
      int j = blk * 128 + jp;
      float val = 0.f;
      if (j < 232) {
        int e = j >> 3, hh = j & 7;
        const float* wvp = wv + (size_t)lL * 157 * 128 + (size_t)(128 + e) * 128 + hh * 16;
        const float* wop = wo + (size_t)lL * 16384 + (size_t)(hh * 16) * 128 + cout;
#pragma unroll
        for (int d = 0; d < 16; d++) val = fmaf(wvp[d], wop[d * 128], val);
      }
      wpe[(size_t)idx] = f2h(val);
    } else if (pb2 < 2880) {
      // ---- conv weight prep
      int idx = (pb2 - 2112) * 256 + tid;
      int kt = idx % 3;
      int rest = idx / 3;
      int i = rest % 128; rest /= 128;
      int oo = rest % 128;
      int s = rest / 128;
      wct[(((size_t)s * 3 + kt) * 128 + oo) * 128 + i] = f2h(pw[idx]);
    } else {
      // ---- h init (virtual grid of 512 blocks)
      int vb = pb2 - 2880;
      if (tid < 128) {
        float s = ebias[tid];
#pragma unroll
        for (int i = 0; i < 27; i++) s += ew[i * 128 + tid];
        hvS[tid] = s;
      }
      __syncthreads();
      size_t total = (size_t)N_TOT * 128;
      for (size_t j = (size_t)vb * 256 + tid; j < total; j += (size_t)512 * 256)
        h[j] = f2h(hvS[j & 127]);
    }
  }
}

// ---------------------------------------------------------------- GEMM helpers (round-4 geometry)
// Ws is LINEAR [128][128] f16, staged by global_load_lds with XOR-swizzled SOURCE;
// reads apply the same involution: chunk c -> c ^ (row & 7)  (chunk = 16B = 8 f16)
template <int NTHR>
__device__ __forceinline__ void stage_w_async(const _Float16* __restrict__ W,
                                              _Float16* Ws, int tid) {
  int wv = tid >> 6, lane = tid & 63;
  constexpr int ITERS = 16384 / (NTHR * 8);
#pragma unroll
  for (int it = 0; it < ITERS; it++) {
    int base = it * (NTHR * 8) + wv * 512;    // f16 units, wave-uniform
    int off = base + lane * 8;                // this lane's linear dest
    int row = off >> 7;
    int cL = (off >> 3) & 15;
    int cS = cL ^ (row & 7);
    const _Float16* src = W + ((size_t)row << 7) + (cS << 3);
    __builtin_amdgcn_global_load_lds(
        (const __attribute__((address_space(1))) void*)src,
        (__attribute__((address_space(3))) void*)(Ws + base), 16, 0, 0);
  }
}
template <int NTHR, int ROWS>
__device__ __forceinline__ void stage_x(const _Float16* __restrict__ src, _Float16* X,
                                        int tid, int rowstride) {
  for (int j = tid; j < ROWS * 16; j += NTHR) {
    int row = j >> 4, seg = (j & 15) * 8;
    *(uint4*)&X[row * 136 + seg] = *(const uint4*)(src + (size_t)row * rowstride + seg);
  }
}
template <bool RESET>
__device__ __forceinline__ void gemm_tile_t(const _Float16* X, const _Float16* Ws,
                                            int wrow, int l16, int quad, f32x4 acc[8]) {
  if (RESET) {
#pragma unroll
    for (int t = 0; t < 8; t++) acc[t] = (f32x4){0.f, 0.f, 0.f, 0.f};
  }
#pragma unroll
  for (int kk = 0; kk < 4; kk++) {
    f16x8 a = *(const f16x8*)&X[(wrow + l16) * 136 + kk * 32 + quad * 8];
#pragma unroll
    for (int t = 0; t < 8; t++) {
      int rw = t * 16 + l16;
      f16x8 b = *(const f16x8*)&Ws[(rw << 7) + ((((kk << 2) + quad) ^ (rw & 7)) << 3)];
      acc[t] = __builtin_amdgcn_mfma_f32_16x16x32_f16(a, b, acc[t], 0, 0, 0);
    }
  }
}

// ---------------------------------------------------------------- fused edge + layer-0 QKV (block-range)
__global__ __launch_bounds__(256) void k_eq(const float* __restrict__ pos,
                                            const float* __restrict__ R,
                                            const int* __restrict__ nbr,
                                            _Float16* __restrict__ edge,
                                            const _Float16* __restrict__ A,
                                            const _Float16* __restrict__ Wqt,
                                            const _Float16* __restrict__ Wkt,
                                            const _Float16* __restrict__ Wvt,
                                            const _Float16* __restrict__ Wqk0,
                                            const _Float16* __restrict__ Wqk1,
                                            _Float16* __restrict__ q, _Float16* __restrict__ hk,
                                            _Float16* __restrict__ hv, _Float16* __restrict__ qkw) {
  __shared__ _Float16 X[64 * 136];
  __shared__ _Float16 Ws[128 * 128];
  int bb = blockIdx.x, tid = threadIdx.x;
  if (bb < EB) {
    // ---- edge features
    int idx = bb * 256 + tid;
    if (idx >= N_TOT * NNBR) return;
    int n = idx / NNBR;
    int m = nbr[idx];
    float dx = pos[m * 3 + 0] - pos[n * 3 + 0];
    float dy = pos[m * 3 + 1] - pos[n * 3 + 1];
    float dz = pos[m * 3 + 2] - pos[n * 3 + 2];
    float d = sqrtf(dx * dx + dy * dy + dz * dz);
    _Float16 eb[32];
#pragma unroll
    for (int j = 0; j < 16; j++) {
      float mu = (20.f / 15.f) * (float)j;
      float t = (d - mu) * 0.8f;
      eb[j] = f2h(__expf(-t * t));
    }
    float inv = 1.f / (d + 1e-8f);
    float ux = dx * inv, uy = dy * inv, uz = dz * inv;
    float Rn[9], Rm[9];
#pragma unroll
    for (int j = 0; j < 9; j++) { Rn[j] = R[(size_t)n * 9 + j]; Rm[j] = R[(size_t)m * 9 + j]; }
#pragma unroll
    for (int cc = 0; cc < 3; cc++)
      eb[16 + cc] = f2h(Rn[0 * 3 + cc] * ux + Rn[1 * 3 + cc] * uy + Rn[2 * 3 + cc] * uz);
#pragma unroll
    for (int cc = 0; cc < 3; cc++)
#pragma unroll
      for (int dd = 0; dd < 3; dd++)
        eb[19 + cc * 3 + dd] = f2h(Rn[0 * 3 + cc] * Rm[0 * 3 + dd] +
                                   Rn[1 * 3 + cc] * Rm[1 * 3 + dd] +
                                   Rn[2 * 3 + cc] * Rm[2 * 3 + dd]);
    eb[28] = f2h((float)(m - n));
    eb[29] = (_Float16)0.f; eb[30] = (_Float16)0.f; eb[31] = (_Float16)0.f;
    _Float16* e = edge + (size_t)idx * 32;
#pragma unroll
    for (int v = 0; v < 4; v++)
      *(uint4*)(e + v * 8) = *(const uint4*)(&eb[v * 8]);
  } else {
    // ---- layer-0 QKV (+qwk), round-4 geometry
    int r0 = (bb - EB) * 64;
    int lane = tid & 63, quad = lane >> 4, l16 = lane & 15, wrow = (tid >> 6) * 16;
    stage_x<256, 64>(A + (size_t)r0 * 128, X, tid, 128);
    const _Float16* wts[5] = {Wqt, Wkt, Wvt, Wqk0, Wqk1};
    f32x4 acc[8];
    for (int w = 0; w < 5; w++) {
      __syncthreads();
      stage_w_async<256>(wts[w], Ws, tid);
      __syncthreads();
      gemm_tile_t<true>(X, Ws, wrow, l16, quad, acc);
#pragma unroll
      for (int t = 0; t < 8; t++) {
        int col = t * 16 + l16;
#pragma unroll
        for (int r = 0; r < 4; r++) {
          float v = acc[t][r];
          int rowg = r0 + wrow + quad * 4 + r;
          if (w < 3) {
            _Float16* C = (w == 0) ? q : (w == 1) ? hk : hv;
            C[(size_t)rowg * 128 + col] = f2h(v);
          } else {
            qkw[(size_t)rowg * 256 + (w - 3) * 128 + col] = f2h(v);
          }
        }
      }
    }
  }
}

// ---------------------------------------------------------------- fused o-proj(+pe) + residual + MLP (+ next QKV+qwk) — round-4 geometry
__global__ __launch_bounds__(256) void k_post(const _Float16* __restrict__ o,
                                              const _Float16* __restrict__ pe_g,
                                              _Float16* __restrict__ h,
                                              const _Float16* __restrict__ Wot,
                                              const _Float16* __restrict__ Wpe0,
                                              const _Float16* __restrict__ Wpe1,
                                              const _Float16* __restrict__ W1t, const float* __restrict__ B1,
                                              const _Float16* __restrict__ W2t, const float* __restrict__ B2,
                                              const _Float16* __restrict__ W3t, const float* __restrict__ B3,
                                              const _Float16* __restrict__ Wqt,
                                              const _Float16* __restrict__ Wkt,
                                              const _Float16* __restrict__ Wvt,
                                              const _Float16* __restrict__ Wqk0,
                                              const _Float16* __restrict__ Wqk1,
                                              _Float16* __restrict__ qo, _Float16* __restrict__ hko,
                                              _Float16* __restrict__ hvo, _Float16* __restrict__ qkwo,
                                              int do_qkv) {
  __shared__ _Float16 X[64 * 136];
  __shared__ _Float16 Ws[128 * 128];
  int tid = threadIdx.x, r0 = blockIdx.x * 64;
  int lane = tid & 63, quad = lane >> 4, l16 = lane & 15, wrow = (tid >> 6) * 16;
  f32x4 acc[8], hres[8];
  stage_x<256, 64>(o + (size_t)r0 * 128, X, tid, 128);
  stage_w_async<256>(Wot, Ws, tid);
  __syncthreads();
  gemm_tile_t<true>(X, Ws, wrow, l16, quad, acc);
  const _Float16* wpes[2] = {Wpe0, Wpe1};
#pragma unroll 1
  for (int blk = 0; blk < 2; blk++) {
    __syncthreads();
    stage_x<256, 64>(pe_g + (size_t)r0 * 256 + blk * 128, X, tid, 256);
    stage_w_async<256>(wpes[blk], Ws, tid);
    __syncthreads();
    gemm_tile_t<false>(X, Ws, wrow, l16, quad, acc);
  }
#pragma unroll
  for (int t = 0; t < 8; t++) {
    int col = t * 16 + l16;
#pragma unroll
    for (int r = 0; r < 4; r++)
      hres[t][r] = acc[t][r] + (float)h[(size_t)(r0 + wrow + quad * 4 + r) * 128 + col];
  }
  __syncthreads();
#pragma unroll
  for (int t = 0; t < 8; t++) {
    int col = t * 16 + l16;
#pragma unroll
    for (int r = 0; r < 4; r++)
      X[(wrow + quad * 4 + r) * 136 + col] = f2h(hres[t][r]);
  }
  stage_w_async<256>(W1t, Ws, tid);
  __syncthreads();
  gemm_tile_t<true>(X, Ws, wrow, l16, quad, acc);
  __syncthreads();
#pragma unroll
  for (int t = 0; t < 8; t++) {
    int col = t * 16 + l16; float bv = B1[col];
#pragma unroll
    for (int r = 0; r < 4; r++)
      X[(wrow + quad * 4 + r) * 136 + col] = f2h(fmaxf(acc[t][r] + bv, 0.f));
  }
  stage_w_async<256>(W2t, Ws, tid);
  __syncthreads();
  gemm_tile_t<true>(X, Ws, wrow, l16, quad, acc);
  __syncthreads();
#pragma unroll
  for (int t = 0; t < 8; t++) {
    int col = t * 16 + l16; float bv = B2[col];
#pragma unroll
    for (int r = 0; r < 4; r++)
      X[(wrow + quad * 4 + r) * 136 + col] = f2h(fmaxf(acc[t][r] + bv, 0.f));
  }
  stage_w_async<256>(W3t, Ws, tid);
  __syncthreads();
  gemm_tile_t<true>(X, Ws, wrow, l16, quad, acc);
  __syncthreads();
#pragma unroll
  for (int t = 0; t < 8; t++) {
    int col = t * 16 + l16; float bv = B3[col];
#pragma unroll
    for (int r = 0; r < 4; r++) {
      float v = hres[t][r] + acc[t][r] + bv;
      h[(size_t)(r0 + wrow + quad * 4 + r) * 128 + col] = f2h(v);
      if (do_qkv) X[(wrow + quad * 4 + r) * 136 + col] = f2h(v);
    }
  }
  if (!do_qkv) return;
  const _Float16* wts[5] = {Wqt, Wkt, Wvt, Wqk0, Wqk1};
  for (int w = 0; w < 5; w++) {
    __syncthreads();
    stage_w_async<256>(wts[w], Ws, tid);
    __syncthreads();
    gemm_tile_t<true>(X, Ws, wrow, l16, quad, acc);
#pragma unroll
    for (int t = 0; t < 8; t++) {
      int col = t * 16 + l16;
#pragma unroll
      for (int r = 0; r < 4; r++) {
        float v = acc[t][r];
        int rowg = r0 + wrow + quad * 4 + r;
        if (w < 3) {
          _Float16* C = (w == 0) ? qo : (w == 1) ? hko : hvo;
          C[(size_t)rowg * 128 + col] = f2h(v);
        } else {
          qkwo[(size_t)rowg * 256 + (w - 3) * 128 + col] = f2h(v);
        }
      }
    }
  }
}

// ---------------------------------------------------------------- attention core: fdot2 QK + wave-parallel softmax
__global__ __launch_bounds__(256) void k_attn(const _Float16* __restrict__ q,
                                              const _Float16* __restrict__ hk,
                                              const _Float16* __restrict__ hv,
                                              const int* __restrict__ nbr,
                                              const _Float16* __restrict__ edge,
                                              const _Float16* __restrict__ qkw,
                                              _Float16* __restrict__ o,
                                              _Float16* __restrict__ pe_g) {
  __shared__ _Float16 elL[4][15 * ELPH];
  __shared__ float etL[4][32 * ETP];
  __shared__ float plL[4][8 * PLP];
  __shared__ int nbL[4][16];
  int tid = threadIdx.x, wave = tid >> 6, lane = tid & 63;
  _Float16* el = elL[wave]; float* et = etL[wave]; float* pl = plL[wave];
  int* nbl = nbL[wave];
  int h8 = lane & 7, k2 = lane >> 3, c2 = lane * 2, h5 = lane >> 3;
  int kst = lane >> 2, gst = lane & 3;
  if (lane < 32) et[lane * ETP + 15] = 0.f;
  int n0 = (blockIdx.x * 4 + wave) * APW;
#pragma unroll 1
  for (int ni = 0; ni < APW; ni++) {
    int n = n0 + ni;
    if (lane < 60) {
      f16x8 ev = *(const f16x8*)(edge + ((size_t)n * 15 + kst) * 32 + gst * 8);
      *(f16x8*)&el[kst * ELPH + gst * 8] = ev;
      int ebs = gst * 8;
      et[(ebs + 0) * ETP + kst] = (float)ev[0];
      et[(ebs + 1) * ETP + kst] = (float)ev[1];
      et[(ebs + 2) * ETP + kst] = (float)ev[2];
      et[(ebs + 3) * ETP + kst] = (float)ev[3];
      et[(ebs + 4) * ETP + kst] = (float)ev[4];
      et[(ebs + 5) * ETP + kst] = (float)ev[5];
      et[(ebs + 6) * ETP + kst] = (float)ev[6];
      et[(ebs + 7) * ETP + kst] = (float)ev[7];
    }
    if (lane < 15) nbl[lane] = nbr[(size_t)n * NNBR + lane];
    const _Float16* qs = qkw + (size_t)n * 256 + h8 * 32;
    f16x8 w0 = *(const f16x8*)qs, w1 = *(const f16x8*)(qs + 8);
    f16x8 w2 = *(const f16x8*)(qs + 16), w3 = *(const f16x8*)(qs + 24);
    const _Float16* qp = q + (size_t)n * 128 + h8 * 16;
    f16x8 qa = *(const f16x8*)qp, qb = *(const f16x8*)(qp + 8);
    CBAR();
#pragma unroll
    for (int p = 0; p < 2; p++) {
      int k = k2 + p * 8;
      if (k < 15) {
        int m = nbl[k];
        const _Float16* hkp = hk + (size_t)m * 128 + h8 * 16;
        f16x8 ha = *(const f16x8*)hkp, hb = *(const f16x8*)(hkp + 8);
        float d0 = 0.f, d1 = 0.f;
        d0 = fdot2(PAIR(qa, 0), PAIR(ha, 0), d0);
        d1 = fdot2(PAIR(qa, 1), PAIR(ha, 1), d1);
        d0 = fdot2(PAIR(qa, 2), PAIR(ha, 2), d0);
        d1 = fdot2(PAIR(qa, 3), PAIR(ha, 3), d1);
        d0 = fdot2(PAIR(qb, 0), PAIR(hb, 0), d0);
        d1 = fdot2(PAIR(qb, 1), PAIR(hb, 1), d1);
        d0 = fdot2(PAIR(qb, 2), PAIR(hb, 2), d0);
        d1 = fdot2(PAIR(qb, 3), PAIR(hb, 3), d1);
        f16x8 l0 = *(const f16x8*)&el[k * ELPH + 0];
        f16x8 l1 = *(const f16x8*)&el[k * ELPH + 8];
        f16x8 l2 = *(const f16x8*)&el[k * ELPH + 16];
        f16x8 l3 = *(const f16x8*)&el[k * ELPH + 24];
        float e0 = 0.f, e1 = 0.f;
        e0 = fdot2(PAIR(l0, 0), PAIR(w0, 0), e0);
        e1 = fdot2(PAIR(l0, 1), PAIR(w0, 1), e1);
        e0 = fdot2(PAIR(l0, 2), PAIR(w0, 2), e0);
        e1 = fdot2(PAIR(l0, 3), PAIR(w0, 3), e1);
        e0 = fdot2(PAIR(l1, 0), PAIR(w1, 0), e0);
        e1 = fdot2(PAIR(l1, 1), PAIR(w1, 1), e1);
        e0 = fdot2(PAIR(l1, 2), PAIR(w1, 2), e0);
        e1 = fdot2(PAIR(l1, 3), PAIR(w1, 3), e1);
        e0 = fdot2(PAIR(l2, 0), PAIR(w2, 0), e0);
        e1 = fdot2(PAIR(l2, 1), PAIR(w2, 1), e1);
        e0 = fdot2(PAIR(l2, 2), PAIR(w2, 2), e0);
        e1 = fdot2(PAIR(l2, 3), PAIR(w2, 3), e1);
        e0 = fdot2(PAIR(l3, 0), PAIR(w3, 0), e0);
        e1 = fdot2(PAIR(l3, 1), PAIR(w3, 1), e1);
        e0 = fdot2(PAIR(l3, 2), PAIR(w3, 2), e0);
        e1 = fdot2(PAIR(l3, 3), PAIR(w3, 3), e1);
        pl[h8 * PLP + k] = fmaf(0.25f, d0 + d1, e0 + e1);
      } else {
        pl[h8 * PLP + 15] = -1e30f;
      }
    }
    CBAR();
    {
      // wave-parallel softmax: lane = (head hh, slot pair g / g+8)
      int hh = lane >> 3, g = lane & 7;
      float va = pl[hh * PLP + g];
      float vb = pl[hh * PLP + 8 + g];
      float mx = fmaxf(va, vb);
      mx = fmaxf(mx, dpp_mov_f32<0xB1>(mx));   // quad_perm xor1
      mx = fmaxf(mx, dpp_mov_f32<0x4E>(mx));   // quad_perm xor2
      mx = fmaxf(mx, dpp_mov_f32<0x141>(mx));  // row_half_mirror (xor4 in 8-group)
      float ea = __expf(va - mx), eb = __expf(vb - mx);
      float s = ea + eb;
      s += dpp_mov_f32<0xB1>(s);
      s += dpp_mov_f32<0x4E>(s);
      s += dpp_mov_f32<0x141>(s);
      float inv = 1.f / s;
      pl[hh * PLP + g] = ea * inv;
      pl[hh * PLP + 8 + g] = eb * inv;
    }
    CBAR();
    _Float16* peo = pe_g + (size_t)n * 256;
#pragma unroll
    for (int p = 0; p < 4; p++) {
      int j = p * 64 + lane;
      float s = 0.f;
      if (j < 232) {
        int e = j >> 3, hh = j & 7;
        f32x4 p0 = *(const f32x4*)&pl[hh * PLP + 0];
        f32x4 p1 = *(const f32x4*)&pl[hh * PLP + 4];
        f32x4 p2 = *(const f32x4*)&pl[hh * PLP + 8];
        f32x4 p3 = *(const f32x4*)&pl[hh * PLP + 12];
        f32x4 t0 = *(const f32x4*)&et[e * ETP + 0];
        f32x4 t1 = *(const f32x4*)&et[e * ETP + 4];
        f32x4 t2 = *(const f32x4*)&et[e * ETP + 8];
        f32x4 t3 = *(const f32x4*)&et[e * ETP + 12];
        s = p0[0]*t0[0] + p0[1]*t0[1] + p0[2]*t0[2] + p0[3]*t0[3]
          + p1[0]*t1[0] + p1[1]*t1[1] + p1[2]*t1[2] + p1[3]*t1[3]
          + p2[0]*t2[0] + p2[1]*t2[1] + p2[2]*t2[2] + p2[3]*t2[3]
          + p3[0]*t3[0] + p3[1]*t3[1] + p3[2]*t3[2] + p3[3]*t3[3];
      }
      peo[j] = f2h(s);
    }
    float pk[16];
    *(f32x4*)&pk[0]  = *(const f32x4*)&pl[h5 * PLP + 0];
    *(f32x4*)&pk[4]  = *(const f32x4*)&pl[h5 * PLP + 4];
    *(f32x4*)&pk[8]  = *(const f32x4*)&pl[h5 * PLP + 8];
    *(f32x4*)&pk[12] = *(const f32x4*)&pl[h5 * PLP + 12];
    float ox = 0.f, oy = 0.f;
#pragma unroll
    for (int k = 0; k < 15; k++) {
      int m = nbl[k];
      f16x2 hh = *(const f16x2*)(hv + (size_t)m * 128 + c2);
      ox = fmaf(pk[k], (float)hh[0], ox);
      oy = fmaf(pk[k], (float)hh[1], oy);
    }
    *(f16x2*)(o + (size_t)n * 128 + c2) = (f16x2){f2h(ox), f2h(oy)};
    CBAR();
  }
}

// ---------------------------------------------------------------- MFMA conv+leaky+residual+maxpool2 (round-4)
__global__ __launch_bounds__(256) void k_convpool_m(const _Float16* __restrict__ x,
                                                    const _Float16* __restrict__ Wc,
                                                    const float* __restrict__ bias,
                                                    _Float16* __restrict__ outp, int Tin) {
  __shared__ _Float16 Xs[66 * 136];
  __shared__ _Float16 Ws[128 * 128];
  int tid = threadIdx.x;
  int b = blockIdx.y;
  int t0 = blockIdx.x * 64;
  for (int j = tid; j < 66 * 16; j += 256) {
    int row = j >> 4, seg = (j & 15) * 8;
    int t = t0 - 1 + row;
    uint4 v = {0u, 0u, 0u, 0u};
    if (t >= 0 && t < Tin) v = *(const uint4*)(x + ((size_t)b * Tin + t) * 128 + seg);
    *(uint4*)&Xs[row * 136 + seg] = v;
  }
  int lane = tid & 63, quad = lane >> 4, l16 = lane & 15, wrow = (tid >> 6) * 16;
  f32x4 acc[8];
#pragma unroll
  for (int t = 0; t < 8; t++) acc[t] = (f32x4){0.f, 0.f, 0.f, 0.f};
  for (int kt = 0; kt < 3; kt++) {
    __syncthreads();
    stage_w_async<256>(Wc + (size_t)kt * 16384, Ws, tid);
    __syncthreads();
#pragma unroll
    for (int kk = 0; kk < 4; kk++) {
      f16x8 a = *(const f16x8*)&Xs[(wrow + l16 + kt) * 136 + kk * 32 + quad * 8];
#pragma unroll
      for (int t = 0; t < 8; t++) {
        int rw = t * 16 + l16;
        f16x8 bfr = *(const f16x8*)&Ws[(rw << 7) + ((((kk << 2) + quad) ^ (rw & 7)) << 3)];
        acc[t] = __builtin_amdgcn_mfma_f32_16x16x32_f16(a, bfr, acc[t], 0, 0, 0);
      }
    }
  }
  int Tout = Tin >> 1;
#pragma unroll
  for (int t = 0; t < 8; t++) {
    int col = t * 16 + l16;
    float bv = bias[col];
#pragma unroll
    for (int rp = 0; rp < 2; rp++) {
      int rl0 = wrow + quad * 4 + rp * 2;
      float y0 = acc[t][rp * 2] + bv;
      float y1 = acc[t][rp * 2 + 1] + bv;
      float z0 = (float)Xs[(rl0 + 1) * 136 + col] + (y0 >= 0.f ? y0 : 0.01f * y0);
      float z1 = (float)Xs[(rl0 + 2) * 136 + col] + (y1 >= 0.f ? y1 : 0.01f * y1);
      outp[((size_t)b * Tout + ((t0 + rl0) >> 1)) * 128 + col] = f2h(fmaxf(z0, z1));
    }
  }
}

// ---------------------------------------------------------------- final reduce (round-4)
__global__ __launch_bounds__(128) void k_final(const _Float16* __restrict__ x,
                                               const float* __restrict__ ew,
                                               const float* __restrict__ ebb,
                                               float* __restrict__ outp) {
  int b = blockIdx.x, cc = threadIdx.x;
  float s = 0.f;
#pragma unroll
  for (int t = 0; t < 32; t++) s += (float)x[((size_t)b * 32 + t) * 128 + cc];
  float v = s * ew[cc];
#pragma unroll
  for (int m = 1; m < 64; m <<= 1) v += __shfl_xor(v, m);
  __shared__ float red[2];
  if ((cc & 63) == 0) red[cc >> 6] = v;
  __syncthreads();
  if (cc == 0) outp[b] = red[0] + red[1] + ebb[0];
}

// ---------------------------------------------------------------- launch
extern "C" void kernel_launch(void* const* d_in, const int* in_sizes, int n_in,
                              void* d_out, int out_size, void* d_ws, size_t ws_size,
                              hipStream_t stream) {
  (void)in_sizes; (void)n_in; (void)out_size; (void)ws_size;
  const float* tert    = (const float*)d_in[0];
  const float* noise   = (const float*)d_in[3];
  const float* embed_w = (const float*)d_in[4];
  const float* embed_b = (const float*)d_in[5];
  const float* wq = (const float*)d_in[6];
  const float* wk = (const float*)d_in[7];
  const float* wv = (const float*)d_in[8];
  const float* wo = (const float*)d_in[9];
  const float* w1 = (const float*)d_in[10];
  const float* b1 = (const float*)d_in[11];
  const float* w2 = (const float*)d_in[12];
  const float* b2 = (const float*)d_in[13];
  const float* w3 = (const float*)d_in[14];
  const float* b3 = (const float*)d_in[15];
  const float* pw = (const float*)d_in[16];
  const float* pb = (const float*)d_in[17];
  const float* ew = (const float*)d_in[18];
  const float* eb = (const float*)d_in[19];
  float* outp = (float*)d_out;

  char* W = (char*)d_ws;
  float* pos  = (float*)W;        W += 393216;     // N*3 f32
  float* R    = (float*)W;        W += 1179648;    // N*9 f32
  int*   nbr  = (int*)W;          W += 1966080;    // N*15 i32
  _Float16* edge = (_Float16*)W;  W += 31457280;   // N*15*32 f16
  _Float16* h    = (_Float16*)W;  W += 8388608;    // N*128 f16
  _Float16* q    = (_Float16*)W;  W += 8388608;
  _Float16* hk   = (_Float16*)W;  W += 8388608;
  _Float16* hv   = (_Float16*)W;  W += 8388608;
  _Float16* o    = (_Float16*)W;  W += 8388608;
  _Float16* qkw_g = (_Float16*)W; W += 16777216;   // N*256 f16
  _Float16* pe_g  = (_Float16*)W; W += 16777216;   // N*256 f16
  _Float16* xa   = (_Float16*)W;  W += 4194304;    // B*256*128 f16
  _Float16* xb   = (_Float16*)W;  W += 2097152;    // B*128*128 f16
  _Float16* wbt  = (_Float16*)W;  W += 688128;     // 21*16384 f16
  _Float16* wqk  = (_Float16*)W;  W += 196608;     // 3*2*16384 f16
  _Float16* wpe  = (_Float16*)W;  W += 196608;     // 3*2*16384 f16
  _Float16* wct  = (_Float16*)W;  W += 393216;     // 12*16384 f16

  k_pre<<<KNB + FRB + PRB, 256, 0, stream>>>(tert, noise, nbr, pos, R,
                                             wq, wk, wv, wo, w1, w2, w3, wbt,
                                             wqk, wpe, pw, wct, embed_w, embed_b, h);

  const _Float16* wt[3][7];
  for (int l = 0; l < 3; l++)
    for (int w = 0; w < 7; w++) wt[l][w] = wbt + (size_t)(l * 7 + w) * 16384;
  const _Float16* wqk_l[3][2];
  const _Float16* wpe_l[3][2];
  for (int l = 0; l < 3; l++)
    for (int bk = 0; bk < 2; bk++) {
      wqk_l[l][bk] = wqk + (size_t)(l * 2 + bk) * 16384;
      wpe_l[l][bk] = wpe + (size_t)(l * 2 + bk) * 16384;
    }

  k_eq<<<EB + 512, 256, 0, stream>>>(pos, R, nbr, edge,
                                     h, wt[0][0], wt[0][1], wt[0][2],
                                     wqk_l[0][0], wqk_l[0][1], q, hk, hv, qkw_g);
  for (int l = 0; l < 3; l++) {
    k_attn<<<1024, 256, 0, stream>>>(q, hk, hv, nbr, edge, qkw_g, o, pe_g);
    int nl = l + 1;
    int do_qkv = (nl < 3) ? 1 : 0;
    k_post<<<512, 256, 0, stream>>>(o, pe_g, h, wt[l][3],
                                    wpe_l[l][0], wpe_l[l][1],
                                    wt[l][4], b1 + l * 128,
                                    wt[l][5], b2 + l * 128,
                                    wt[l][6], b3 + l * 128,
                                    do_qkv ? wt[nl][0] : nullptr,
                                    do_qkv ? wt[nl][1] : nullptr,
                                    do_qkv ? wt[nl][2] : nullptr,
                                    do_qkv ? wqk_l[nl][0] : nullptr,
                                    do_qkv ? wqk_l[nl][1] : nullptr,
                                    q, hk, hv, qkw_g, do_qkv);
  }

  k_convpool_m<<<dim3(8, 64), 256, 0, stream>>>(h,  wct + 0 * 49152, pb + 0,   xa, 512);
  k_convpool_m<<<dim3(4, 64), 256, 0, stream>>>(xa, wct + 1 * 49152, pb + 128, xb, 256);
  k_convpool_m<<<dim3(2, 64), 256, 0, stream>>>(xb, wct + 2 * 49152, pb + 256, xa, 128);
  k_convpool_m<<<dim3(1, 64), 256, 0, stream>>>(xa, wct + 3 * 49152, pb + 384, xb, 64);
  k_final<<<64, 128, 0, stream>>>(xb, ew, eb, outp);
}